// Round 28
// baseline (513.871 us; speedup 1.0000x reference)
//
#include <hip/hip_runtime.h>
#include <math.h>

#define TPB 256

typedef _Float16 h8 __attribute__((ext_vector_type(8)));
typedef float f4 __attribute__((ext_vector_type(4)));
typedef unsigned short ushort_t;

__device__ __forceinline__ unsigned short f2bf(float x) {
  unsigned int u = __float_as_uint(x);
  unsigned int r = (u + 0x7fffu + ((u >> 16) & 1u)) >> 16;
  return (unsigned short)r;
}
__device__ __forceinline__ float bf2f(unsigned short h) {
  return __uint_as_float(((unsigned int)h) << 16);
}
__device__ __forceinline__ ushort_t f2h(float x) {
  _Float16 h = (_Float16)x;
  return *(ushort_t*)&h;
}
__device__ __forceinline__ float h2f(ushort_t u) {
  _Float16 h = *(_Float16*)&u;
  return (float)h;
}
// 16-bit order-preserving key of the fp16 representation
__device__ __forceinline__ unsigned key16_of(float x) {
  unsigned h = (unsigned)f2h(x);
  return h ^ ((h >> 15) ? 0xFFFFu : 0x8000u);
}
__device__ __forceinline__ ushort_t un_key16(unsigned k) {
  return (ushort_t)(k ^ ((k & 0x8000u) ? 0x8000u : 0xFFFFu));
}

// ===== 8x8 max pool =====
__global__ __launch_bounds__(TPB) void pool8_kernel(const float* __restrict__ in,
                                                    float* __restrict__ out, int total) {
  int idx = blockIdx.x * TPB + threadIdx.x;
  if (idx >= total) return;
  int b = idx / 2304, yx = idx - b * 2304;
  int y = yx / 48, x = yx - y * 48;
  const float* p = in + ((size_t)b * 384 + (size_t)y * 8) * 384 + (size_t)x * 8;
  float m = -INFINITY;
#pragma unroll
  for (int i = 0; i < 8; ++i)
#pragma unroll
    for (int j = 0; j < 8; ++j) m = fmaxf(m, p[(size_t)i * 384 + j]);
  out[idx] = m;
}

// ===== NCHW fp32 -> [HW][C] fp32 transpose (also used for kg1 2304x2304) =====
__global__ __launch_bounds__(TPB) void tposef_kernel(const float* __restrict__ src,
                                                     float* __restrict__ dst, int C, int HW,
                                                     int DS) {
  __shared__ float tile[64][65];
  int px0 = blockIdx.x * 64;
  int c0 = blockIdx.y * 64;
  int b = blockIdx.z;
  int tid = threadIdx.x;
#pragma unroll
  for (int i = 0; i < 16; ++i) {
    int c = (tid >> 6) + i * 4, p = tid & 63;
    tile[c][p] = src[((size_t)b * C + c0 + c) * HW + px0 + p];
  }
  __syncthreads();
#pragma unroll
  for (int i = 0; i < 16; ++i) {
    int c = tid & 63, p = (tid >> 6) + i * 4;
    dst[((size_t)b * HW + px0 + p) * DS + c0 + c] = tile[c][p];
  }
}

// ===== guarded transpose (C not multiple of 64), e.g. klp 289 channels =====
__global__ __launch_bounds__(TPB) void tposeg_kernel(const float* __restrict__ src,
                                                     float* __restrict__ dst, int C, int HW,
                                                     int DS) {
  __shared__ float tile[64][65];
  int px0 = blockIdx.x * 64;
  int c0 = blockIdx.y * 64;
  int b = blockIdx.z;
  int tid = threadIdx.x;
#pragma unroll
  for (int i = 0; i < 16; ++i) {
    int c = (tid >> 6) + i * 4, p = tid & 63;
    float v = 0.f;
    if (c0 + c < C) v = src[((size_t)b * C + c0 + c) * HW + px0 + p];
    tile[c][p] = v;
  }
  __syncthreads();
#pragma unroll
  for (int i = 0; i < 16; ++i) {
    int c = tid & 63, p = (tid >> 6) + i * 4;
    if (c0 + c < C)
      dst[((size_t)b * HW + px0 + p) * DS + c0 + c] = tile[c][p];
  }
}

// ===== NCHW fp32 -> NHWC fp16 transpose =====
__global__ __launch_bounds__(TPB) void tposeh_kernel(const float* __restrict__ src,
                                                     ushort_t* __restrict__ dst, int C, int HW,
                                                     int DS) {
  __shared__ float tile[64][65];
  int px0 = blockIdx.x * 64;
  int c0 = blockIdx.y * 64;
  int b = blockIdx.z;
  int tid = threadIdx.x;
#pragma unroll
  for (int i = 0; i < 16; ++i) {
    int c = (tid >> 6) + i * 4, p = tid & 63;
    tile[c][p] = src[((size_t)b * C + c0 + c) * HW + px0 + p];
  }
  __syncthreads();
#pragma unroll
  for (int i = 0; i < 16; ++i) {
    int c = tid & 63, p = (tid >> 6) + i * 4;
    dst[((size_t)b * HW + px0 + p) * DS + c0 + c] = f2h(tile[c][p]);
  }
}

// ===== global top-k on 16-bit fp16 keys: ONE WAVE per (pixel, F/B) task =====
// 4 tasks/block (2 pixels x {fg,bg}); per-wave histograms, compaction, bitonic.
// Zero block barriers — fully wave-synchronous. Output identical to fused version.
__global__ __launch_bounds__(TPB) void topk_global_kernel(const float* __restrict__ kgT,
                                                          const float* __restrict__ gm,
                                                          ushort_t* __restrict__ xcat) {
  __shared__ unsigned hist[4][256];
  __shared__ ushort_t sout[4][256];
  __shared__ unsigned selT[4], selA[4];
  __shared__ unsigned cntG[4], cntE[4];
  const int lane = threadIdx.x & 63;
  const int wid = threadIdx.x >> 6;
  const int task = blockIdx.x * 4 + wid;  // (b*2304+yx)*2 + fb
  const int pix = task >> 1;
  const int fb = task & 1;
  const int b = pix / 2304, yx = pix - b * 2304;
  const float* kp = kgT + ((size_t)b * 2304 + yx) * 2304;
  const float* gp = gm + (size_t)b * 2304;
  unsigned kk[36];
#pragma unroll
  for (int e = 0; e < 36; ++e) {
    int i = e * 64 + lane;
    float v = kp[i];
    float g = gp[i];
    kk[e] = key16_of(v * (fb ? (1.0f - g) : g));
  }
  unsigned* h = hist[wid];
  // ---- pass 0: high byte ----
#pragma unroll
  for (int q = 0; q < 4; ++q) h[lane * 4 + q] = 0;
  __builtin_amdgcn_wave_barrier();
#pragma unroll
  for (int e = 0; e < 36; ++e) atomicAdd(&h[kk[e] >> 8], 1u);
  __builtin_amdgcn_wave_barrier();
  {
    unsigned h0 = h[4 * lane], h1 = h[4 * lane + 1];
    unsigned h2 = h[4 * lane + 2], h3 = h[4 * lane + 3];
    unsigned x = h0 + h1 + h2 + h3;
#pragma unroll
    for (int d = 1; d < 64; d <<= 1) {
      unsigned y = __shfl_down(x, d, 64);
      if (lane + d < 64) x += y;
    }
    unsigned long long m = __ballot(x >= 256u);
    int tl = 63 - __clzll(m);
    if (lane == tl) {
      unsigned s1 = x - h0, s2 = s1 - h1, s3 = s2 - h2, s4 = s3 - h3;
      int jj;
      unsigned A;
      if (s3 >= 256u) { jj = 3; A = s4; }
      else if (s2 >= 256u) { jj = 2; A = s3; }
      else if (s1 >= 256u) { jj = 1; A = s2; }
      else { jj = 0; A = s1; }
      selT[wid] = 4 * tl + jj;
      selA[wid] = A;
    }
  }
  __builtin_amdgcn_wave_barrier();
  const unsigned T0 = selT[wid], gt0 = selA[wid];
  const unsigned K1 = 256u - gt0;
  // ---- pass 1: low byte among elements matching high byte ----
#pragma unroll
  for (int q = 0; q < 4; ++q) h[lane * 4 + q] = 0;
  __builtin_amdgcn_wave_barrier();
#pragma unroll
  for (int e = 0; e < 36; ++e)
    if ((kk[e] >> 8) == T0) atomicAdd(&h[kk[e] & 0xFFu], 1u);
  __builtin_amdgcn_wave_barrier();
  {
    unsigned h0 = h[4 * lane], h1 = h[4 * lane + 1];
    unsigned h2 = h[4 * lane + 2], h3 = h[4 * lane + 3];
    unsigned x = h0 + h1 + h2 + h3;
#pragma unroll
    for (int d = 1; d < 64; d <<= 1) {
      unsigned y = __shfl_down(x, d, 64);
      if (lane + d < 64) x += y;
    }
    unsigned long long m = __ballot(x >= K1);
    int tl = 63 - __clzll(m);
    if (lane == tl) {
      unsigned s1 = x - h0, s2 = s1 - h1, s3 = s2 - h2, s4 = s3 - h3;
      int jj;
      unsigned A;
      if (s3 >= K1) { jj = 3; A = s4; }
      else if (s2 >= K1) { jj = 2; A = s3; }
      else if (s1 >= K1) { jj = 1; A = s2; }
      else { jj = 0; A = s1; }
      selT[wid] = 4 * tl + jj;
      selA[wid] = A;
    }
  }
  __builtin_amdgcn_wave_barrier();
  const unsigned tK = (T0 << 8) | selT[wid];
  const unsigned nGT = gt0 + selA[wid], need = 256u - nGT;
  if (lane == 0) { cntG[wid] = 0; cntE[wid] = 0; }
  __builtin_amdgcn_wave_barrier();
  ushort_t* sarr = sout[wid];
#pragma unroll
  for (int e = 0; e < 36; ++e) {
    unsigned k = kk[e];
    if (k > tK) sarr[atomicAdd(&cntG[wid], 1u)] = (ushort_t)k;
    else if (k == tK) {
      unsigned ee = atomicAdd(&cntE[wid], 1u);
      if (ee < need) sarr[nGT + ee] = (ushort_t)tK;
    }
  }
  __builtin_amdgcn_wave_barrier();
  // ---- per-wave bitonic sort of 256 (ascending) ----
  for (int kkk = 2; kkk <= 256; kkk <<= 1) {
    for (int j = kkk >> 1; j > 0; j >>= 1) {
#pragma unroll
      for (int r = 0; r < 2; ++r) {
        int p = lane + r * 64;
        int t = (p & (j - 1)) | ((p & ~(j - 1)) << 1);
        int ixj = t | j;
        bool up = ((t & kkk) == 0);
        ushort_t a = sarr[t], c = sarr[ixj];
        if (up ? (a > c) : (a < c)) { sarr[t] = c; sarr[ixj] = a; }
      }
      __builtin_amdgcn_wave_barrier();
    }
  }
  size_t base = ((size_t)pix) * 1312 + (fb ? 512 : 256);
#pragma unroll
  for (int r = 0; r < 4; ++r) {
    int t = lane + r * 64;
    xcat[base + t] = un_key16((unsigned)sarr[255 - t]);
  }
}

// ===== local top-k: ONE WAVE per (pixel, F/B) — in-register bitonic of 512 =====
__global__ __launch_bounds__(TPB) void topk_local_kernel(const float* __restrict__ klpT,
                                                         const float* __restrict__ lm,
                                                         ushort_t* __restrict__ xcat) {
  const int lane = threadIdx.x & 63;
  const int wid = threadIdx.x >> 6;
  const int pix = blockIdx.x * 2 + (wid >> 1);
  const int fb = wid & 1;  // 0 = fg, 1 = bg
  const int b = pix / 2304;
  const int yx = pix - b * 2304;
  const int y = yx / 48, x = yx - y * 48;
  const float* kp = klpT + (size_t)pix * 320;
  float v8[8];
#pragma unroll
  for (int r = 0; r < 8; ++r) {
    int i = r * 64 + lane;
    float vv = -INFINITY;
    if (i < 289) {
      int dy = i / 17, dx = i - dy * 17;
      int sy = y + dy - 8, sx = x + dx - 8;
      float pv = 0.f;
      if (sy >= 0 && sy < 48 && sx >= 0 && sx < 48) pv = lm[(size_t)b * 2304 + sy * 48 + sx];
      float v = kp[i];
      vv = v * (fb ? (1.0f - pv) : pv);
    }
    v8[r] = vv;
  }
  for (int k = 2; k <= 512; k <<= 1) {
    for (int j = k >> 1; j > 0; j >>= 1) {
      if (j >= 64) {
        const int jr = j >> 6;
#pragma unroll
        for (int r = 0; r < 8; ++r) {
          if ((r & jr) == 0) {
            const int rp = r | jr;
            bool up = (((unsigned)(r * 64) & (unsigned)k) == 0);
            float a = v8[r], c = v8[rp];
            if (up) {
              v8[r] = fminf(a, c); v8[rp] = fmaxf(a, c);
            } else {
              v8[r] = fmaxf(a, c); v8[rp] = fminf(a, c);
            }
          }
        }
      } else {
        bool lower = ((lane & j) == 0);
#pragma unroll
        for (int r = 0; r < 8; ++r) {
          float p = __shfl_xor(v8[r], j, 64);
          bool up = (((unsigned)(r * 64 + lane) & (unsigned)k) == 0);
          bool takeMin = (lower == up);
          v8[r] = takeMin ? fminf(v8[r], p) : fmaxf(v8[r], p);
        }
      }
    }
  }
  size_t base = (size_t)pix * 1312 + (fb ? 1024 : 768);
#pragma unroll
  for (int r = 4; r < 8; ++r) {
    int t = 511 - (r * 64 + lane);
    xcat[base + t] = f2h(v8[r]);
  }
}

// ===== pm channel + zero pad channels of xcat (fp16) =====
__global__ __launch_bounds__(TPB) void pm_pad_kernel(const float* __restrict__ lm,
                                                     ushort_t* __restrict__ xcat) {
  int idx = blockIdx.x * TPB + threadIdx.x;
  if (idx >= 2 * 2304 * 32) return;
  int ch = idx & 31;
  int r = idx >> 5;
  xcat[(size_t)r * 1312 + 1280 + ch] = (ch == 0) ? f2h(lm[r]) : (ushort_t)0;
}

// ===== mega weight preconvert: all convs, single fp16 =====
struct WallDesc {
  const float* src[13];
  int CinW[13], CIP[13], CoutPad[13], CoutReal[13];
  unsigned start[14];
  int n;
};
__global__ __launch_bounds__(TPB) void wconv_all_kernel(WallDesc D, ushort_t* __restrict__ whi,
                                                        int total) {
  int i = blockIdx.x * TPB + threadIdx.x;
  if (i >= total) return;
  int k = 0;
  while (k + 1 < D.n && (unsigned)i >= D.start[k + 1]) ++k;
  int j = i - D.start[k];
  int e = j & 7;
  int t = j >> 3;
  int l16 = t & 15; t >>= 4;
  int h4 = t & 3; t >>= 2;
  int NCOG = D.CoutPad[k] >> 4;
  int cog = t % NCOG; t /= NCOG;
  int kykx = t % 9;
  int chunk = t / 9;
  int co = cog * 16 + l16;
  int ci = chunk * 32 + h4 * 8 + e;
  float v = 0.f;
  if (ci < D.CinW[k] && co < D.CoutReal[k])
    v = D.src[k][((size_t)co * D.CinW[k] + ci) * 9 + kykx];
  whi[i] = f2h(v);
}

// ===== apply norm(+res) to an 8-channel fp16 vector (used by fused staging) =====
// NORM: 1 = relu((x-m)*i); 2 = +fp16 res; 3 = +fp32 res
template <int NORM>
__device__ __forceinline__ uint4 norm8(uint4 v, const float* __restrict__ nmean,
                                       const float* __restrict__ ninv,
                                       const void* __restrict__ nres, size_t mb,
                                       size_t pxoff) {
  float f[8];
  f[0] = h2f((ushort_t)(v.x & 0xffff)); f[1] = h2f((ushort_t)(v.x >> 16));
  f[2] = h2f((ushort_t)(v.y & 0xffff)); f[3] = h2f((ushort_t)(v.y >> 16));
  f[4] = h2f((ushort_t)(v.z & 0xffff)); f[5] = h2f((ushort_t)(v.z >> 16));
  f[6] = h2f((ushort_t)(v.w & 0xffff)); f[7] = h2f((ushort_t)(v.w >> 16));
  float4 m0 = *(const float4*)(nmean + mb);
  float4 m1 = *(const float4*)(nmean + mb + 4);
  float4 i0 = *(const float4*)(ninv + mb);
  float4 i1 = *(const float4*)(ninv + mb + 4);
  float o[8];
  o[0] = fmaxf((f[0] - m0.x) * i0.x, 0.f);
  o[1] = fmaxf((f[1] - m0.y) * i0.y, 0.f);
  o[2] = fmaxf((f[2] - m0.z) * i0.z, 0.f);
  o[3] = fmaxf((f[3] - m0.w) * i0.w, 0.f);
  o[4] = fmaxf((f[4] - m1.x) * i1.x, 0.f);
  o[5] = fmaxf((f[5] - m1.y) * i1.y, 0.f);
  o[6] = fmaxf((f[6] - m1.z) * i1.z, 0.f);
  o[7] = fmaxf((f[7] - m1.w) * i1.w, 0.f);
  if (NORM == 2) {
    uint4 rv = *(const uint4*)((const ushort_t*)nres + pxoff);
    o[0] += h2f((ushort_t)(rv.x & 0xffff)); o[1] += h2f((ushort_t)(rv.x >> 16));
    o[2] += h2f((ushort_t)(rv.y & 0xffff)); o[3] += h2f((ushort_t)(rv.y >> 16));
    o[4] += h2f((ushort_t)(rv.z & 0xffff)); o[5] += h2f((ushort_t)(rv.z >> 16));
    o[6] += h2f((ushort_t)(rv.w & 0xffff)); o[7] += h2f((ushort_t)(rv.w >> 16));
  } else if (NORM == 3) {
    const float* rp = (const float*)nres + pxoff;
    float4 r0 = *(const float4*)rp;
    float4 r1 = *(const float4*)(rp + 4);
    o[0] += r0.x; o[1] += r0.y; o[2] += r0.z; o[3] += r0.w;
    o[4] += r1.x; o[5] += r1.y; o[6] += r1.z; o[7] += r1.w;
  }
  uint4 out;
  out.x = (unsigned)f2h(o[0]) | ((unsigned)f2h(o[1]) << 16);
  out.y = (unsigned)f2h(o[2]) | ((unsigned)f2h(o[3]) << 16);
  out.z = (unsigned)f2h(o[4]) | ((unsigned)f2h(o[5]) << 16);
  out.w = (unsigned)f2h(o[6]) | ((unsigned)f2h(o[7]) << 16);
  return out;
}

// ===== MFMA implicit-GEMM 3x3 conv, fp16 NHWC act (raw), single fp16 weights =====
// GEOM 0: tile 16x8, 4 waves = 2co x 2px, MB=MFR*32. GEOM 1: tile 8x8, MB=64, MFR=1.
// NORM: 0 none; 1 norm; 2 norm+fp16res; 3 norm+fp32res;
//       5 bilinear(src) upsample (src dims hin,win, scale rs).
// STAT=1 (S==1): per-tile channel sum/sumsq of STORED outputs.
// Split-K partials stored as packed fp16.
template <int MFR, int ACT, int STAT, int GEOM, int NORM>
__global__ __launch_bounds__(TPB) void conv_mfma_kernel(
    const ushort_t* __restrict__ in, const ushort_t* __restrict__ whi,
    const float* __restrict__ bias,
    ushort_t* __restrict__ outh, float* __restrict__ outf, ushort_t* __restrict__ partial,
    float* __restrict__ stat, int ntiles,
    const float* __restrict__ nmean, const float* __restrict__ ninv,
    const void* __restrict__ nres,
    int hin, int win, float rs,
    int CIP, int Cout, int H, int W, int S, int ci_per_s) {
  const int NPIX = (GEOM == 1) ? 100 : 180;
  const int PITCH = 10;
  __shared__ uint4 sB[(GEOM == 1) ? 800 : 1440];
  const int MB = (GEOM == 1) ? 64 : MFR * 32;
  const int tid = threadIdx.x;
  const int lane = tid & 63;
  const int lo16 = lane & 15, hi4 = lane >> 4;
  const int wid = tid >> 6;
  const int wco = (GEOM == 1) ? wid : (wid & 1);
  const int wpx = (GEOM == 1) ? 0 : (wid >> 1);
  const int tilesX = W >> 3;
  const int tx0 = (blockIdx.x % tilesX) << 3;
  const int ty0 = (blockIdx.x / tilesX) << ((GEOM == 1) ? 3 : 4);
  const int s = blockIdx.y % S;
  const int co0 = (blockIdx.y / S) * MB;
  const int b = blockIdx.z;
  const int NCOG = Cout >> 4;
  const size_t HW = (size_t)H * W;
  const ushort_t* inb = in + (size_t)b * HW * CIP;
  const ushort_t* srcb = in + (size_t)b * hin * win * CIP;  // for NORM==5
  int ci_begin = s * ci_per_s;
  int ci_end = ci_begin + ci_per_s;
  if (ci_end > CIP) ci_end = CIP;
  f4 acc[MFR][4];
#pragma unroll
  for (int m = 0; m < MFR; ++m)
#pragma unroll
    for (int n = 0; n < 4; ++n) acc[m][n] = (f4){0.f, 0.f, 0.f, 0.f};

  for (int ci0 = ci_begin; ci0 < ci_end; ci0 += 64) {
    const bool has2 = (ci0 + 32 < ci_end);
    __syncthreads();
#pragma unroll
    for (int it = 0; it < 6; ++it) {
      int u = it * TPB + tid;
      if (u < NPIX * 8) {
        int q4 = u / NPIX;
        int pix = u - q4 * NPIX;
        int prow = pix / PITCH, pcol = pix - prow * PITCH;
        int gy = ty0 - 1 + prow, gx = tx0 - 1 + pcol;
        int ci = ci0 + q4 * 8;
        bool inbp = (ci < CIP && gy >= 0 && gy < H && gx >= 0 && gx < W);
        uint4 v = {0u, 0u, 0u, 0u};
        if (inbp) {
          if (NORM <= 3) {
            v = *(const uint4*)(inb + ((size_t)gy * W + gx) * CIP + ci);
            if (NORM != 0) {
              size_t mb = (size_t)b * CIP + ci;
              size_t pxoff = ((size_t)b * HW + (size_t)gy * W + gx) * CIP + ci;
              v = norm8<NORM>(v, nmean, ninv, nres, mb, pxoff);
            }
          } else {
            float ys = gy * rs, xs = gx * rs;
            int y0 = (int)floorf(ys);
            if (y0 > hin - 1) y0 = hin - 1;
            int x0 = (int)floorf(xs);
            if (x0 > win - 1) x0 = win - 1;
            int y1 = y0 + 1 < hin ? y0 + 1 : hin - 1;
            int x1 = x0 + 1 < win ? x0 + 1 : win - 1;
            float wy = ys - (float)y0, wx = xs - (float)x0;
            uint4 s00 = *(const uint4*)(srcb + ((size_t)y0 * win + x0) * CIP + ci);
            uint4 s01 = *(const uint4*)(srcb + ((size_t)y0 * win + x1) * CIP + ci);
            uint4 s10 = *(const uint4*)(srcb + ((size_t)y1 * win + x0) * CIP + ci);
            uint4 s11 = *(const uint4*)(srcb + ((size_t)y1 * win + x1) * CIP + ci);
            float w00 = (1.f - wy) * (1.f - wx), w01 = (1.f - wy) * wx;
            float w10 = wy * (1.f - wx), w11 = wy * wx;
            union U8 { uint4 q; ushort_t sv[8]; };
            U8 u00, u01, u10, u11, uo;
            u00.q = s00; u01.q = s01; u10.q = s10; u11.q = s11;
#pragma unroll
            for (int k8 = 0; k8 < 8; ++k8) {
              float val = h2f(u00.sv[k8]) * w00 + h2f(u01.sv[k8]) * w01 +
                          h2f(u10.sv[k8]) * w10 + h2f(u11.sv[k8]) * w11;
              uo.sv[k8] = f2h(val);
            }
            v = uo.q;
          }
        }
        sB[q4 * NPIX + pix] = v;
      }
    }
    __syncthreads();
#pragma unroll
    for (int h = 0; h < 2; ++h) {
      if (h == 1 && !has2) continue;
      const int chunkIdx = (ci0 >> 5) + h;
#pragma unroll
      for (int ky = 0; ky < 3; ++ky) {
#pragma unroll
        for (int kx = 0; kx < 3; ++kx) {
          const int kykx = ky * 3 + kx;
          h8 ah[MFR];
#pragma unroll
          for (int m = 0; m < MFR; ++m) {
            int cog = (co0 + wco * (GEOM == 1 ? 16 : (MB / 2)) + m * 16) >> 4;
            size_t woff = (((size_t)chunkIdx * 9 + kykx) * NCOG + cog) * 512 + (size_t)lane * 8;
            ah[m] = *(const h8*)(whi + woff);
          }
          h8 bf[4];
#pragma unroll
          for (int n = 0; n < 4; ++n) {
            int pix = (wpx * 8 + n * 2 + (lo16 >> 3) + ky) * PITCH + (lo16 & 7) + kx;
            union { uint4 q; h8 v; } ub;
            ub.q = sB[(h * 4 + hi4) * NPIX + pix];
            bf[n] = ub.v;
          }
#pragma unroll
          for (int m = 0; m < MFR; ++m)
#pragma unroll
            for (int n = 0; n < 4; ++n)
              acc[m][n] = __builtin_amdgcn_mfma_f32_16x16x32_f16(ah[m], bf[n], acc[m][n], 0, 0, 0);
        }
      }
    }
  }

#pragma unroll
  for (int m = 0; m < MFR; ++m) {
#pragma unroll
    for (int n = 0; n < 4; ++n) {
      int py = ty0 + wpx * 8 + n * 2 + (lo16 >> 3);
      int pxx = tx0 + (lo16 & 7);
      int co_r0 = co0 + wco * (GEOM == 1 ? 16 : (MB / 2)) + m * 16 + hi4 * 4;
      if (ACT == 1) {
        if (wco == 0 && m == 0 && hi4 == 0) {
          float v = acc[0][n][0] + bias[0];
          outf[(size_t)b * HW + (size_t)py * W + pxx] = 1.0f / (1.0f + expf(-v));
        }
      } else if (S == 1) {
        float4 bv = *(const float4*)(bias + co_r0);
        unsigned w0 = (unsigned)f2h(acc[m][n][0] + bv.x) |
                      ((unsigned)f2h(acc[m][n][1] + bv.y) << 16);
        unsigned w1 = (unsigned)f2h(acc[m][n][2] + bv.z) |
                      ((unsigned)f2h(acc[m][n][3] + bv.w) << 16);
        uint2 o = {w0, w1};
        *(uint2*)(outh + (((size_t)b * HW + (size_t)py * W + pxx) * Cout + co_r0)) = o;
        if (STAT) {
          acc[m][n][0] = h2f((ushort_t)(w0 & 0xffff));
          acc[m][n][1] = h2f((ushort_t)(w0 >> 16));
          acc[m][n][2] = h2f((ushort_t)(w1 & 0xffff));
          acc[m][n][3] = h2f((ushort_t)(w1 >> 16));
        }
      } else {
        uint2 o;
        o.x = (unsigned)f2h(acc[m][n][0]) | ((unsigned)f2h(acc[m][n][1]) << 16);
        o.y = (unsigned)f2h(acc[m][n][2]) | ((unsigned)f2h(acc[m][n][3]) << 16);
        *(uint2*)(partial + (((size_t)(s * 2 + b) * HW + (size_t)py * W + pxx) * Cout + co_r0)) = o;
      }
    }
  }

  if (STAT) {
    __syncthreads();
    f4* lredS = (f4*)sB;
    f4* lredQ = lredS + 32;
    if (GEOM == 1) {
      f4 sv = acc[0][0] + acc[0][1] + acc[0][2] + acc[0][3];
      f4 qv = acc[0][0] * acc[0][0] + acc[0][1] * acc[0][1] + acc[0][2] * acc[0][2] +
              acc[0][3] * acc[0][3];
#pragma unroll
      for (int off = 1; off < 16; off <<= 1) {
#pragma unroll
        for (int kq = 0; kq < 4; ++kq) {
          sv[kq] += __shfl_xor(sv[kq], off, 64);
          qv[kq] += __shfl_xor(qv[kq], off, 64);
        }
      }
      if (lo16 == 0) {
        lredS[wid * 4 + hi4] = sv;
        lredQ[wid * 4 + hi4] = qv;
      }
      __syncthreads();
      if (tid < 16) {
        int widT = tid >> 2, h4T = tid & 3;
        int c = co0 + widT * 16 + h4T * 4;
        size_t sbase = ((size_t)b * ntiles + blockIdx.x) * (size_t)(Cout * 2);
        *(f4*)(stat + sbase + c) = lredS[tid];
        *(f4*)(stat + sbase + Cout + c) = lredQ[tid];
      }
    } else {
#pragma unroll
      for (int m = 0; m < MFR; ++m) {
        f4 sv = acc[m][0] + acc[m][1] + acc[m][2] + acc[m][3];
        f4 qv = acc[m][0] * acc[m][0] + acc[m][1] * acc[m][1] + acc[m][2] * acc[m][2] +
                acc[m][3] * acc[m][3];
#pragma unroll
        for (int off = 1; off < 16; off <<= 1) {
#pragma unroll
          for (int kq = 0; kq < 4; ++kq) {
            sv[kq] += __shfl_xor(sv[kq], off, 64);
            qv[kq] += __shfl_xor(qv[kq], off, 64);
          }
        }
        if (lo16 == 0) {
          lredS[(wid * MFR + m) * 4 + hi4] = sv;
          lredQ[(wid * MFR + m) * 4 + hi4] = qv;
        }
      }
      __syncthreads();
      if (tid < 2 * MFR * 4) {
        int wcoT = tid / (MFR * 4);
        int r = tid % (MFR * 4);
        int mT = r / 4;
        int h4T = r % 4;
        f4 sv = lredS[((wcoT)*MFR + mT) * 4 + h4T] + lredS[((wcoT + 2) * MFR + mT) * 4 + h4T];
        f4 qv = lredQ[((wcoT)*MFR + mT) * 4 + h4T] + lredQ[((wcoT + 2) * MFR + mT) * 4 + h4T];
        int c = co0 + wcoT * (MB / 2) + mT * 16 + h4T * 4;
        size_t sbase = ((size_t)b * ntiles + blockIdx.x) * (size_t)(Cout * 2);
        *(f4*)(stat + sbase + c) = sv;
        *(f4*)(stat + sbase + Cout + c) = qv;
      }
    }
  }
}

// ===== scalar pred head: norm(zB raw) -> conv3x3 64->1 + sigmoid =====
__global__ __launch_bounds__(TPB) void pred_kernel(const ushort_t* __restrict__ in,
                                                   const float* __restrict__ w,
                                                   const float* __restrict__ bias,
                                                   const float* __restrict__ nmean,
                                                   const float* __restrict__ ninv,
                                                   float* __restrict__ outp) {
  __shared__ uint4 hal[324 * 9];
  __shared__ float wl[576];
  const int tid = threadIdx.x;
  const int tx0 = (blockIdx.x % 12) * 16;
  const int ty0 = (blockIdx.x / 12) * 16;
  const int b = blockIdx.y;
  const ushort_t* inb = in + (size_t)b * 36864 * 64;
  for (int u = tid; u < 576; u += TPB) {
    int ci = u & 63, kk = u >> 6;
    wl[u] = w[(size_t)ci * 9 + kk];
  }
  for (int u = tid; u < 2592; u += TPB) {
    int px = u >> 3, q4 = u & 7;
    int r = px / 18, c = px - r * 18;
    int gy = ty0 - 1 + r, gx = tx0 - 1 + c;
    uint4 v = {0u, 0u, 0u, 0u};
    if (gy >= 0 && gy < 192 && gx >= 0 && gx < 192) {
      v = *(const uint4*)(inb + ((size_t)gy * 192 + gx) * 64 + q4 * 8);
      v = norm8<1>(v, nmean, ninv, nullptr, (size_t)b * 64 + q4 * 8, 0);
    }
    hal[px * 9 + q4] = v;
  }
  __syncthreads();
  const int ty = tid >> 4, tx = tid & 15;
  float acc = bias[0];
#pragma unroll
  for (int ky = 0; ky < 3; ++ky) {
#pragma unroll
    for (int kx = 0; kx < 3; ++kx) {
      int base = ((ty + ky) * 18 + tx + kx) * 9;
      const float* wp = &wl[(ky * 3 + kx) * 64];
#pragma unroll
      for (int q = 0; q < 8; ++q) {
        uint4 v = hal[base + q];
        const float* w8 = wp + q * 8;
        acc = fmaf(h2f((ushort_t)(v.x & 0xffff)), w8[0], acc);
        acc = fmaf(h2f((ushort_t)(v.x >> 16)), w8[1], acc);
        acc = fmaf(h2f((ushort_t)(v.y & 0xffff)), w8[2], acc);
        acc = fmaf(h2f((ushort_t)(v.y >> 16)), w8[3], acc);
        acc = fmaf(h2f((ushort_t)(v.z & 0xffff)), w8[4], acc);
        acc = fmaf(h2f((ushort_t)(v.z >> 16)), w8[5], acc);
        acc = fmaf(h2f((ushort_t)(v.w & 0xffff)), w8[6], acc);
        acc = fmaf(h2f((ushort_t)(v.w >> 16)), w8[7], acc);
      }
    }
  }
  outp[(size_t)b * 36864 + (size_t)(ty0 + ty) * 192 + (tx0 + tx)] =
      1.0f / (1.0f + expf(-acc));
}

// ===== split-K reduce + bias -> fp16 NHWC (fp16 packed partials) =====
template <int STAT>
__global__ __launch_bounds__(TPB) void reduce_nhwc_kernel(const ushort_t* __restrict__ partial,
                                                          const float* __restrict__ bias,
                                                          ushort_t* __restrict__ outh,
                                                          float* __restrict__ stat, int bpb,
                                                          int S, int Cout, int HW, int total4) {
  int i = blockIdx.x * TPB + threadIdx.x;
  float4 accv = {0.f, 0.f, 0.f, 0.f};
  unsigned w0 = 0, w1 = 0;
  int e = i * 4;
  int CHW = Cout * HW;
  if (i < total4) {
    int b = e / CHW;
    int rem = e - b * CHW;
    int co = e % Cout;
    for (int ss = 0; ss < S; ++ss) {
      const uint2 t2 = *(const uint2*)(partial + (size_t)(ss * 2 + b) * CHW + rem);
      accv.x += h2f((ushort_t)(t2.x & 0xffff));
      accv.y += h2f((ushort_t)(t2.x >> 16));
      accv.z += h2f((ushort_t)(t2.y & 0xffff));
      accv.w += h2f((ushort_t)(t2.y >> 16));
    }
    float4 bv = *(const float4*)(bias + co);
    w0 = (unsigned)f2h(accv.x + bv.x) | ((unsigned)f2h(accv.y + bv.y) << 16);
    w1 = (unsigned)f2h(accv.z + bv.z) | ((unsigned)f2h(accv.w + bv.w) << 16);
    uint2 o = {w0, w1};
    *(uint2*)(outh + (size_t)b * CHW + rem) = o;
  }
  if (STAT) {
    __shared__ f4 ls[4][16], lq[4][16];
    const int tid = threadIdx.x;
    const int lane = tid & 63, wv = tid >> 6;
    f4 r;
    r[0] = h2f((ushort_t)(w0 & 0xffff));
    r[1] = h2f((ushort_t)(w0 >> 16));
    r[2] = h2f((ushort_t)(w1 & 0xffff));
    r[3] = h2f((ushort_t)(w1 >> 16));
    f4 sv = r;
    f4 qv = r * r;
#pragma unroll
    for (int kq = 0; kq < 4; ++kq) {
      sv[kq] += __shfl_down(sv[kq], 16, 64);
      qv[kq] += __shfl_down(qv[kq], 16, 64);
      sv[kq] += __shfl_down(sv[kq], 32, 64);
      qv[kq] += __shfl_down(qv[kq], 32, 64);
    }
    if (lane < 16) {
      ls[wv][lane] = sv;
      lq[wv][lane] = qv;
    }
    __syncthreads();
    if (tid < 16) {
      f4 S4 = ls[0][tid] + ls[1][tid] + ls[2][tid] + ls[3][tid];
      f4 Q4 = lq[0][tid] + lq[1][tid] + lq[2][tid] + lq[3][tid];
      int b = (blockIdx.x * (TPB * 4)) / CHW;
      int tblk = blockIdx.x - b * bpb;
      int c = tid * 4;
      size_t sbase = ((size_t)b * bpb + tblk) * (size_t)(Cout * 2);
      *(f4*)(stat + sbase + c) = S4;
      *(f4*)(stat + sbase + Cout + c) = Q4;
    }
  }
}

// ===== InstanceNorm stats (fp16 NHWC path, for non-fused inorms) =====
__global__ __launch_bounds__(TPB) void in_stats_kernel(const ushort_t* __restrict__ x,
                                                       float* __restrict__ stat, int N, int C) {
  __shared__ float ls[4][64], lq[4][64];
  int CG = C >> 6;
  int b = blockIdx.x / CG, cg = blockIdx.x % CG;
  int slice = blockIdx.y;
  int c = threadIdx.x & 63, p = threadIdx.x >> 6;
  int cnt = N >> 6;
  int base = slice * cnt;
  float s = 0.f, q = 0.f;
  const ushort_t* xp = x + ((size_t)b * N) * C + cg * 64 + c;
  for (int px = base + p; px < base + cnt; px += 4) {
    float v = h2f(xp[(size_t)px * C]);
    s += v;
    q = fmaf(v, v, q);
  }
  ls[p][c] = s;
  lq[p][c] = q;
  __syncthreads();
  if (threadIdx.x < 64) {
    float S = ls[0][threadIdx.x] + ls[1][threadIdx.x] + ls[2][threadIdx.x] + ls[3][threadIdx.x];
    float Q = lq[0][threadIdx.x] + lq[1][threadIdx.x] + lq[2][threadIdx.x] + lq[3][threadIdx.x];
    int Ctot = 2 * C;
    int idx = b * C + cg * 64 + threadIdx.x;
    stat[(size_t)(slice * Ctot + idx) * 2] = S;
    stat[(size_t)(slice * Ctot + idx) * 2 + 1] = Q;
  }
}

__global__ __launch_bounds__(TPB) void in_final_kernel(const float* __restrict__ stat,
                                                       float* __restrict__ mean,
                                                       float* __restrict__ inv, int N, int Ctot) {
  int idx = blockIdx.x * TPB + threadIdx.x;
  if (idx >= Ctot) return;
  float S = 0.f, Q = 0.f;
  for (int sl = 0; sl < 64; ++sl) {
    S += stat[(size_t)(sl * Ctot + idx) * 2];
    Q += stat[(size_t)(sl * Ctot + idx) * 2 + 1];
  }
  float m = S / (float)N;
  float var = Q / (float)N - m * m;
  if (var < 0.f) var = 0.f;
  mean[idx] = m;
  inv[idx] = 1.0f / sqrtf(var + 1e-5f);
}

// ===== finalize from per-tile stats: ONE BLOCK PER (b,c) =====
__global__ __launch_bounds__(TPB) void in_final_tiles_kernel(const float* __restrict__ stat,
                                                             float* __restrict__ mean,
                                                             float* __restrict__ inv, int N,
                                                             int C, int ntiles) {
  __shared__ float rs_[TPB], rq_[TPB];
  int idx = blockIdx.x;  // b*C + c
  int b = idx / C, c = idx % C;
  float S = 0.f, Q = 0.f;
  for (int t = threadIdx.x; t < ntiles; t += TPB) {
    size_t base = ((size_t)b * ntiles + t) * (size_t)(C * 2);
    S += stat[base + c];
    Q += stat[base + C + c];
  }
  rs_[threadIdx.x] = S;
  rq_[threadIdx.x] = Q;
  __syncthreads();
  for (int off = TPB / 2; off > 0; off >>= 1) {
    if (threadIdx.x < off) {
      rs_[threadIdx.x] += rs_[threadIdx.x + off];
      rq_[threadIdx.x] += rq_[threadIdx.x + off];
    }
    __syncthreads();
  }
  if (threadIdx.x == 0) {
    float ma = rs_[0] / (float)N;
    float var = rq_[0] / (float)N - ma * ma;
    if (var < 0.f) var = 0.f;
    mean[idx] = ma;
    inv[idx] = 1.0f / sqrtf(var + 1e-5f);
  }
}

// ===== bilinear resize align_corners, fp16 NHWC; NORM=1 normalizes samples first =====
template <int NORM>
__global__ __launch_bounds__(TPB) void resize4_kernel(const ushort_t* __restrict__ in,
                                                      ushort_t* __restrict__ out,
                                                      const float* __restrict__ nmean,
                                                      const float* __restrict__ ninv, int C,
                                                      int hin, int win, int Hout, int Wout,
                                                      float r, int total4) {
  for (int i = blockIdx.x * TPB + threadIdx.x; i < total4; i += gridDim.x * TPB) {
    int e = i * 4;
    int c = e % C;
    int t = e / C;
    int X = t % Wout;
    int t2 = t / Wout;
    int Y = t2 % Hout;
    int b = t2 / Hout;
    float ys = Y * r, xs = X * r;
    int y0 = (int)floorf(ys);
    if (y0 > hin - 1) y0 = hin - 1;
    int x0 = (int)floorf(xs);
    if (x0 > win - 1) x0 = win - 1;
    int y1 = y0 + 1 < hin ? y0 + 1 : hin - 1;
    int x1 = x0 + 1 < win ? x0 + 1 : win - 1;
    float wy = ys - (float)y0, wx = xs - (float)x0;
    const ushort_t* ip = in + ((size_t)b * hin * win) * C + c;
    uint2 a2 = *(const uint2*)(ip + ((size_t)y0 * win + x0) * C);
    uint2 b2 = *(const uint2*)(ip + ((size_t)y0 * win + x1) * C);
    uint2 c2 = *(const uint2*)(ip + ((size_t)y1 * win + x0) * C);
    uint2 d2 = *(const uint2*)(ip + ((size_t)y1 * win + x1) * C);
    float av[4], bv[4], cv[4], dv[4];
    av[0] = h2f((ushort_t)(a2.x & 0xffff)); av[1] = h2f((ushort_t)(a2.x >> 16));
    av[2] = h2f((ushort_t)(a2.y & 0xffff)); av[3] = h2f((ushort_t)(a2.y >> 16));
    bv[0] = h2f((ushort_t)(b2.x & 0xffff)); bv[1] = h2f((ushort_t)(b2.x >> 16));
    bv[2] = h2f((ushort_t)(b2.y & 0xffff)); bv[3] = h2f((ushort_t)(b2.y >> 16));
    cv[0] = h2f((ushort_t)(c2.x & 0xffff)); cv[1] = h2f((ushort_t)(c2.x >> 16));
    cv[2] = h2f((ushort_t)(c2.y & 0xffff)); cv[3] = h2f((ushort_t)(c2.y >> 16));
    dv[0] = h2f((ushort_t)(d2.x & 0xffff)); dv[1] = h2f((ushort_t)(d2.x >> 16));
    dv[2] = h2f((ushort_t)(d2.y & 0xffff)); dv[3] = h2f((ushort_t)(d2.y >> 16));
    if (NORM) {
      float4 m4 = *(const float4*)(nmean + (size_t)b * C + c);
      float4 i4 = *(const float4*)(ninv + (size_t)b * C + c);
      float mm[4] = {m4.x, m4.y, m4.z, m4.w};
      float ii[4] = {i4.x, i4.y, i4.z, i4.w};
#pragma unroll
      for (int k = 0; k < 4; ++k) {
        av[k] = fmaxf((av[k] - mm[k]) * ii[k], 0.f);
        bv[k] = fmaxf((bv[k] - mm[k]) * ii[k], 0.f);
        cv[k] = fmaxf((cv[k] - mm[k]) * ii[k], 0.f);
        dv[k] = fmaxf((dv[k] - mm[k]) * ii[k], 0.f);
      }
    }
    float w00 = (1.f - wy) * (1.f - wx), w01 = (1.f - wy) * wx;
    float w10 = wy * (1.f - wx), w11 = wy * wx;
    float o[4];
#pragma unroll
    for (int k = 0; k < 4; ++k)
      o[k] = av[k] * w00 + bv[k] * w01 + cv[k] * w10 + dv[k] * w11;
    uint2 ov;
    ov.x = (unsigned)f2h(o[0]) | ((unsigned)f2h(o[1]) << 16);
    ov.y = (unsigned)f2h(o[2]) | ((unsigned)f2h(o[3]) << 16);
    *(uint2*)(out + e) = ov;
  }
}

extern "C" void kernel_launch(void* const* d_in, const int* in_sizes, int n_in,
                              void* d_out, int out_size, void* d_ws, size_t ws_size,
                              hipStream_t stream) {
  (void)in_sizes; (void)n_in; (void)out_size;
  const float* p3 = (const float*)d_in[0];
  const float* p2 = (const float*)d_in[1];
  const float* p1 = (const float*)d_in[2];
  const float* kg1 = (const float*)d_in[3];
  const float* klp = (const float*)d_in[4];
  const float* key_mask = (const float*)d_in[5];
  const float* pre_mask = (const float*)d_in[6];
  const float* conv_top_w = (const float*)d_in[7];
  const float* conv_top_b = (const float*)d_in[8];
  const float* aic_top_w1 = (const float*)d_in[9];
  const float* aic_top_b1 = (const float*)d_in[10];
  const float* aic_top_w2 = (const float*)d_in[11];
  const float* aic_top_b2 = (const float*)d_in[12];
  const float* r1a_w1 = (const float*)d_in[13];
  const float* r1a_b1 = (const float*)d_in[14];
  const float* r1a_w2 = (const float*)d_in[15];
  const float* r1a_b2 = (const float*)d_in[16];
  const float* r1b_w1 = (const float*)d_in[17];
  const float* r1b_b1 = (const float*)d_in[18];
  const float* r1b_w2 = (const float*)d_in[19];
  const float* r1b_b2 = (const float*)d_in[20];
  const float* r2a_w1 = (const float*)d_in[21];
  const float* r2a_b1 = (const float*)d_in[22];
  const float* r2a_w2 = (const float*)d_in[23];
  const float* r2a_b2 = (const float*)d_in[24];
  const float* r2b_w1 = (const float*)d_in[25];
  const float* r2b_b1 = (const float*)d_in[26];
  const float* r2b_w2 = (const float*)d_in[27];
  const float* r2b_b2 = (const float*)d_in[28];
  const float* dec_w = (const float*)d_in[29];
  const float* dec_b = (const float*)d_in[30];
  const float* pred_w = (const float*)d_in[31];
  const float* pred_b = (const float*)d_in[32];
  float* outp = (float*)d_out;

  // workspace layout (float units)
  const size_t OFF_GM = 0;
  const size_t OFF_LM = 4608;
  const size_t OFF_STAT = 9216;       // 294912 f
  const size_t OFF_MEAN = 304128;     // 512
  const size_t OFF_INV = 304640;      // 512
  const size_t OFF_WB = 305152;       // 4,239,360 f window (fp16 weights use half)
  const size_t OFF_AH0 = 4544512;     // 3,022,848 f  xcat/y96
  const size_t OFF_AH1 = 7567360;     // 589,824 f    a0/h96/d96
  const size_t OFF_AH2 = 8157184;     // 147,456 f    h48
  const size_t OFF_AH3 = 8304640;     // 589,824 f    a1
  const size_t OFF_AH4 = 8894464;     // 2,359,296 f  R1/zA   (kgT + PbufTop window)
  const size_t OFF_AH5 = 11253760;    // 2,359,296 f  R0/zB
  const size_t OFF_P1T = 13613056;    // 4,718,592 f  partials(fp16) / p1t / klpT
  const size_t OFF_P2T = 18331648;    // 1,179,648 f  p2t (fp16)
  const size_t TOTAL_F = 19511296;    // ~78 MB
  if (ws_size < TOTAL_F * sizeof(float)) return;

  float* ws = (float*)d_ws;
  float* gm = ws + OFF_GM;
  float* lm = ws + OFF_LM;
  float* statb = ws + OFF_STAT;
  float* meanb = ws + OFF_MEAN;
  float* invb = ws + OFF_INV;
  ushort_t* wbh = (ushort_t*)(ws + OFF_WB);
  ushort_t* xcat_h = (ushort_t*)(ws + OFF_AH0);
  ushort_t* y96_h = (ushort_t*)(ws + OFF_AH0);
  ushort_t* a0_h = (ushort_t*)(ws + OFF_AH1);
  ushort_t* h96_h = (ushort_t*)(ws + OFF_AH1);
  ushort_t* d96_h = (ushort_t*)(ws + OFF_AH1);
  ushort_t* h48_h = (ushort_t*)(ws + OFF_AH2);
  ushort_t* a1_h = (ushort_t*)(ws + OFF_AH3);
  ushort_t* R1_h = (ushort_t*)(ws + OFF_AH4);
  ushort_t* zA_h = (ushort_t*)(ws + OFF_AH4);
  ushort_t* R0_h = (ushort_t*)(ws + OFF_AH5);
  ushort_t* zB_h = (ushort_t*)(ws + OFF_AH5);
  ushort_t* Pbuf16 = (ushort_t*)(ws + OFF_P1T);     // fp16 partials (small convs)
  ushort_t* PbufTop16 = (ushort_t*)(ws + OFF_AH4);  // conv_top S=7 fp16 partials
  float* p1t = ws + OFF_P1T;
  ushort_t* p2t = (ushort_t*)(ws + OFF_P2T);
  float* kgT = ws + OFF_AH4;          // AH4..end window (pre-conv only)
  float* klpT = ws + OFF_P1T;         // INSIDE kgT window -> consume BEFORE kg1 transpose

  // ---- mega weight conversion (single fp16) ----
  WallDesc D;
  const float* wsrc[13] = {conv_top_w, aic_top_w1, aic_top_w2, r1a_w1, r1a_w2, r1b_w1,
                           r1b_w2, dec_w, r2a_w1, r2a_w2, r2b_w1, r2b_w2, pred_w};
  const int wcin[13] = {1281, 256, 64, 256, 64, 256, 64, 256, 64, 64, 64, 64, 64};
  const int wcip[13] = {1312, 256, 64, 256, 64, 256, 64, 256, 64, 64, 64, 64, 64};
  const int wcop[13] = {256, 64, 256, 64, 256, 64, 256, 64, 64, 64, 64, 64, 64};
  const int wcor[13] = {256, 64, 256, 64, 256, 64, 256, 64, 64, 64, 64, 64, 1};
  unsigned cum = 0;
  unsigned woff[13];
  for (int k = 0; k < 13; ++k) {
    D.src[k] = wsrc[k];
    D.CinW[k] = wcin[k];
    D.CIP[k] = wcip[k];
    D.CoutPad[k] = wcop[k];
    D.CoutReal[k] = wcor[k];
    D.start[k] = cum;
    woff[k] = cum;
    cum += (unsigned)(wcop[k] * 9 * wcip[k]);
  }
  D.start[13] = cum;
  D.n = 13;
  wconv_all_kernel<<<(cum + TPB - 1) / TPB, TPB, 0, stream>>>(D, wbh, (int)cum);

  // ---- pooled masks, correlation transposes, xcat assembly ----
  pool8_kernel<<<(2 * 2304 + TPB - 1) / TPB, TPB, 0, stream>>>(key_mask, gm, 2 * 2304);
  pool8_kernel<<<(2 * 2304 + TPB - 1) / TPB, TPB, 0, stream>>>(pre_mask, lm, 2 * 2304);
  tposeg_kernel<<<dim3(36, 5, 2), TPB, 0, stream>>>(klp, klpT, 289, 2304, 320);
  topk_local_kernel<<<2304, TPB, 0, stream>>>(klpT, lm, xcat_h);
  tposef_kernel<<<dim3(36, 36, 2), TPB, 0, stream>>>(kg1, kgT, 2304, 2304, 2304);
  topk_global_kernel<<<2304, TPB, 0, stream>>>(kgT, gm, xcat_h);
  tposeh_kernel<<<dim3(36, 4, 2), TPB, 0, stream>>>(p3, xcat_h, 256, 2304, 1312);
  pm_pad_kernel<<<(2 * 2304 * 32 + TPB - 1) / TPB, TPB, 0, stream>>>(lm, xcat_h);

  // geom: 0 = 16x8 tile (MB 64/128), 1 = 8x8 tile MB=64 MFR=1 (always STAT).
  // normMode: 0 none, 1 norm, 2 norm+fp16res, 3 norm+fp32res,
  //           5 bilinear(src)    [src dims hin x win, scale rsc]
  auto conv = [&](const ushort_t* src, int wk, const float* bb, ushort_t* dsth,
                  ushort_t* part, int CIP, int CoutPad, int H, int W, int S, int MB,
                  int geom, int redStat, int normMode, const void* res, int hin, int win,
                  float rsc) {
    const ushort_t* whiK = wbh + woff[wk];
    int chunks = CIP / 32;
    int cps = ((chunks + S - 1) / S) * 32;
    if (geom == 1) {
      int ntiles = (W / 8) * (H / 8);
      dim3 grid(ntiles, CoutPad / 64, 2);
      if (normMode == 1)
        conv_mfma_kernel<1, 0, 1, 1, 1><<<grid, TPB, 0, stream>>>(
            src, whiK, bb, dsth, nullptr, nullptr, statb, ntiles, meanb, invb, res,
            hin, win, rsc, CIP, CoutPad, H, W, 1, cps);
      else if (normMode == 3)
        conv_mfma_kernel<1, 0, 1, 1, 3><<<grid, TPB, 0, stream>>>(
            src, whiK, bb, dsth, nullptr, nullptr, statb, ntiles, meanb, invb, res,
            hin, win, rsc, CIP, CoutPad, H, W, 1, cps);
      else if (normMode == 5)
        conv_mfma_kernel<1, 0, 1, 1, 5><<<grid, TPB, 0, stream>>>(
            src, whiK, bb, dsth, nullptr, nullptr, statb, ntiles, meanb, invb, res,
            hin, win, rsc, CIP, CoutPad, H, W, 1, cps);
      else
        conv_mfma_kernel<1, 0, 1, 1, 0><<<grid, TPB, 0, stream>>>(
            src, whiK, bb, dsth, nullptr, nullptr, statb, ntiles, meanb, invb, res,
            hin, win, rsc, CIP, CoutPad, H, W, 1, cps);
      return;
    }
    int ntiles = (W / 8) * (H / 16);
    dim3 grid(ntiles, (CoutPad / MB) * S, 2);
    if (MB == 128)
      conv_mfma_kernel<4, 0, 0, 0, 0><<<grid, TPB, 0, stream>>>(
          src, whiK, bb, dsth, nullptr, part, nullptr, 0, meanb, invb, res, hin, win,
          rsc, CIP, CoutPad, H, W, S, cps);
    else if (normMode == 1)
      conv_mfma_kernel<2, 0, 0, 0, 1><<<grid, TPB, 0, stream>>>(
          src, whiK, bb, dsth, nullptr, part, nullptr, 0, meanb, invb, res, hin, win,
          rsc, CIP, CoutPad, H, W, S, cps);
    else if (normMode == 2)
      conv_mfma_kernel<2, 0, 0, 0, 2><<<grid, TPB, 0, stream>>>(
          src, whiK, bb, dsth, nullptr, part, nullptr, 0, meanb, invb, res, hin, win,
          rsc, CIP, CoutPad, H, W, S, cps);
    else
      conv_mfma_kernel<2, 0, 0, 0, 0><<<grid, TPB, 0, stream>>>(
          src, whiK, bb, dsth, nullptr, part, nullptr, 0, meanb, invb, res, hin, win,
          rsc, CIP, CoutPad, H, W, S, cps);
    if (S > 1) {
      int HW = H * W;
      int total4 = 2 * CoutPad * HW / 4;
      int nblk = (total4 + TPB - 1) / TPB;
      int bpb = (CoutPad * HW) / (TPB * 4);
      if (redStat)
        reduce_nhwc_kernel<1><<<nblk, TPB, 0, stream>>>(part, bb, dsth, statb, bpb, S,
                                                        CoutPad, HW, total4);
      else
        reduce_nhwc_kernel<0><<<nblk, TPB, 0, stream>>>(part, bb, dsth, nullptr, 0, S,
                                                        CoutPad, HW, total4);
    }
  };
  auto stats_plain = [&](ushort_t* x, int C, int N) {
    dim3 g1(2 * (C / 64), 64);
    in_stats_kernel<<<g1, TPB, 0, stream>>>(x, statb, N, C);
    int Ctot = 2 * C;
    in_final_kernel<<<(Ctot + TPB - 1) / TPB, TPB, 0, stream>>>(statb, meanb, invb, N, Ctot);
  };
  auto stats_tiles = [&](int C, int N, int ntiles) {
    in_final_tiles_kernel<<<2 * C, TPB, 0, stream>>>(statb, meanb, invb, N, C, ntiles);
  };

  // ---- top fuse @48 ----
  conv(xcat_h, 0, conv_top_b, a0_h, PbufTop16, 1312, 256, 48, 48, 7, 128, 0, 0, 0, nullptr,
       48, 48, 1.f);
  conv(a0_h, 1, aic_top_b1, h48_h, Pbuf16, 256, 64, 48, 48, 8, 64, 0, 1, 0, nullptr, 48, 48,
       1.f);
  stats_tiles(64, 2304, 144);                                     // h48 stats -> meanb
  conv(h48_h, 2, aic_top_b2, a1_h, Pbuf16, 64, 256, 48, 48, 2, 64, 0, 0, 1, nullptr, 48, 48,
       1.f);
  stats_plain(a1_h, 256, 2304);                                   // a1 stats -> meanb

  // ---- 48 -> 96: separate resize (normalizes a1 on the fly) -> y96 ----
  {
    int total4 = 2 * 96 * 96 * 256 / 4;
    int g = (total4 + TPB - 1) / TPB; if (g > 4096) g = 4096;
    resize4_kernel<1><<<g, TPB, 0, stream>>>(a1_h, y96_h, meanb, invb, 256, 48, 48, 96, 96,
                                             47.f / 95.f, total4);
  }
  conv(y96_h, 3, r1a_b1, h96_h, Pbuf16, 256, 64, 96, 96, 4, 64, 0, 1, 0, nullptr, 96, 96,
       1.f);
  tposeh_kernel<<<dim3(144, 4, 2), TPB, 0, stream>>>(p2, p2t, 256, 9216, 256);
  stats_tiles(64, 9216, 576);                                     // h96 stats -> meanb
  conv(h96_h, 4, r1a_b2, R1_h, nullptr, 64, 256, 96, 96, 1, 64, 1, 0, 1, nullptr, 96, 96,
       1.f);
  stats_tiles(256, 9216, 144);                                    // R1 stats -> meanb
  conv(R1_h, 5, r1b_b1, h96_h, Pbuf16, 256, 64, 96, 96, 4, 64, 0, 1, 2, p2t, 96, 96, 1.f);
  stats_tiles(64, 9216, 576);                                     // h96 stats -> meanb
  conv(h96_h, 6, r1b_b2, R0_h, nullptr, 64, 256, 96, 96, 1, 64, 1, 0, 1, nullptr, 96, 96,
       1.f);
  stats_tiles(256, 9216, 144);                                    // R0 stats -> meanb
  conv(R0_h, 7, dec_b, d96_h, Pbuf16, 256, 64, 96, 96, 4, 64, 0, 0, 1, nullptr, 96, 96,
       1.f);
  tposef_kernel<<<dim3(576, 1, 2), TPB, 0, stream>>>(p1, p1t, 64, 36864, 64);

  // ---- 96 -> 192: r2a_w1 reads bilinear(d96) directly (fused resize) ----
  conv(d96_h, 8, r2a_b1, zA_h, nullptr, 64, 64, 192, 192, 1, 64, 1, 0, 5, nullptr, 96, 96,
       95.f / 191.f);
  stats_tiles(64, 36864, 576);                                    // zA stats -> meanb
  conv(zA_h, 9, r2a_b2, zB_h, nullptr, 64, 64, 192, 192, 1, 64, 1, 0, 1, nullptr, 192, 192,
       1.f);
  stats_tiles(64, 36864, 576);                                    // zB stats -> meanb
  conv(zB_h, 10, r2b_b1, zA_h, nullptr, 64, 64, 192, 192, 1, 64, 1, 0, 3, p1t, 192, 192,
       1.f);
  stats_tiles(64, 36864, 576);                                    // zA stats -> meanb
  conv(zA_h, 11, r2b_b2, zB_h, nullptr, 64, 64, 192, 192, 1, 64, 1, 0, 1, nullptr, 192, 192,
       1.f);
  stats_tiles(64, 36864, 576);                                    // zB stats -> meanb

  // ---- pred head: norm(zB) -> 64 -> 1 + sigmoid -> d_out (NCHW [2,1,192,192]) ----
  pred_kernel<<<dim3(144, 2), TPB, 0, stream>>>(zB_h, pred_w, pred_b, meanb, invb, outp);
}

// Round 29
// 500.618 us; speedup vs baseline: 1.0265x; 1.0265x over previous
//
#include <hip/hip_runtime.h>
#include <math.h>

#define TPB 256

typedef _Float16 h8 __attribute__((ext_vector_type(8)));
typedef float f4 __attribute__((ext_vector_type(4)));
typedef unsigned short ushort_t;

__device__ __forceinline__ unsigned short f2bf(float x) {
  unsigned int u = __float_as_uint(x);
  unsigned int r = (u + 0x7fffu + ((u >> 16) & 1u)) >> 16;
  return (unsigned short)r;
}
__device__ __forceinline__ float bf2f(unsigned short h) {
  return __uint_as_float(((unsigned int)h) << 16);
}
__device__ __forceinline__ ushort_t f2h(float x) {
  _Float16 h = (_Float16)x;
  return *(ushort_t*)&h;
}
__device__ __forceinline__ float h2f(ushort_t u) {
  _Float16 h = *(_Float16*)&u;
  return (float)h;
}
// 16-bit order-preserving key of the fp16 representation
__device__ __forceinline__ unsigned key16_of(float x) {
  unsigned h = (unsigned)f2h(x);
  return h ^ ((h >> 15) ? 0xFFFFu : 0x8000u);
}
__device__ __forceinline__ ushort_t un_key16(unsigned k) {
  return (ushort_t)(k ^ ((k & 0x8000u) ? 0x8000u : 0xFFFFu));
}

// ===== 8x8 max pool =====
__global__ __launch_bounds__(TPB) void pool8_kernel(const float* __restrict__ in,
                                                    float* __restrict__ out, int total) {
  int idx = blockIdx.x * TPB + threadIdx.x;
  if (idx >= total) return;
  int b = idx / 2304, yx = idx - b * 2304;
  int y = yx / 48, x = yx - y * 48;
  const float* p = in + ((size_t)b * 384 + (size_t)y * 8) * 384 + (size_t)x * 8;
  float m = -INFINITY;
#pragma unroll
  for (int i = 0; i < 8; ++i)
#pragma unroll
    for (int j = 0; j < 8; ++j) m = fmaxf(m, p[(size_t)i * 384 + j]);
  out[idx] = m;
}

// ===== NCHW fp32 -> [HW][C] fp32 transpose (also used for kg1 2304x2304) =====
__global__ __launch_bounds__(TPB) void tposef_kernel(const float* __restrict__ src,
                                                     float* __restrict__ dst, int C, int HW,
                                                     int DS) {
  __shared__ float tile[64][65];
  int px0 = blockIdx.x * 64;
  int c0 = blockIdx.y * 64;
  int b = blockIdx.z;
  int tid = threadIdx.x;
#pragma unroll
  for (int i = 0; i < 16; ++i) {
    int c = (tid >> 6) + i * 4, p = tid & 63;
    tile[c][p] = src[((size_t)b * C + c0 + c) * HW + px0 + p];
  }
  __syncthreads();
#pragma unroll
  for (int i = 0; i < 16; ++i) {
    int c = tid & 63, p = (tid >> 6) + i * 4;
    dst[((size_t)b * HW + px0 + p) * DS + c0 + c] = tile[c][p];
  }
}

// ===== guarded transpose (C not multiple of 64) -> fp16 output (klp 289 ch) =====
__global__ __launch_bounds__(TPB) void tposegh_kernel(const float* __restrict__ src,
                                                      ushort_t* __restrict__ dst, int C,
                                                      int HW, int DS) {
  __shared__ float tile[64][65];
  int px0 = blockIdx.x * 64;
  int c0 = blockIdx.y * 64;
  int b = blockIdx.z;
  int tid = threadIdx.x;
#pragma unroll
  for (int i = 0; i < 16; ++i) {
    int c = (tid >> 6) + i * 4, p = tid & 63;
    float v = 0.f;
    if (c0 + c < C) v = src[((size_t)b * C + c0 + c) * HW + px0 + p];
    tile[c][p] = v;
  }
  __syncthreads();
#pragma unroll
  for (int i = 0; i < 16; ++i) {
    int c = tid & 63, p = (tid >> 6) + i * 4;
    if (c0 + c < C)
      dst[((size_t)b * HW + px0 + p) * DS + c0 + c] = f2h(tile[c][p]);
  }
}

// ===== NCHW fp32 -> NHWC fp16 transpose =====
__global__ __launch_bounds__(TPB) void tposeh_kernel(const float* __restrict__ src,
                                                     ushort_t* __restrict__ dst, int C, int HW,
                                                     int DS) {
  __shared__ float tile[64][65];
  int px0 = blockIdx.x * 64;
  int c0 = blockIdx.y * 64;
  int b = blockIdx.z;
  int tid = threadIdx.x;
#pragma unroll
  for (int i = 0; i < 16; ++i) {
    int c = (tid >> 6) + i * 4, p = tid & 63;
    tile[c][p] = src[((size_t)b * C + c0 + c) * HW + px0 + p];
  }
  __syncthreads();
#pragma unroll
  for (int i = 0; i < 16; ++i) {
    int c = tid & 63, p = (tid >> 6) + i * 4;
    dst[((size_t)b * HW + px0 + p) * DS + c0 + c] = f2h(tile[c][p]);
  }
}

// ===== fused top-k: GLOBAL (2 of 3 blocks) + LOCAL (1 of 3 blocks) in one launch =====
// Flavor by blockIdx: g%3<2 -> global task bid=(g/3)*2+(g%3); else local 2 pixels.
// Global: R27 fused F/B 2-pass radix + wave bitonic. Local: in-register bitonic 512.
__global__ __launch_bounds__(TPB) void topk_all_kernel(const float* __restrict__ kgT,
                                                       const float* __restrict__ gm,
                                                       const ushort_t* __restrict__ klpT16,
                                                       const float* __restrict__ lm,
                                                       ushort_t* __restrict__ xcat) {
  __shared__ unsigned histF[4][256], histB[4][256];
  __shared__ ushort_t soutF[256], soutB[256];
  __shared__ unsigned selT[2], selA[2];
  __shared__ unsigned cntG[2], cntE[2];
  const int tid = threadIdx.x;
  const int lane = tid & 63, wid = tid >> 6;
  const int g = blockIdx.x;
  const int fl = g % 3;
  if (fl < 2) {
    // ================= GLOBAL task =================
    int bid = (g / 3) * 2 + fl;
    int b = bid / 2304, yx = bid - b * 2304;
    const float* kp = kgT + ((size_t)b * 2304 + yx) * 2304;
    const float* gp = gm + (size_t)b * 2304;
    unsigned kF[9], kB[9];
#pragma unroll
    for (int j = 0; j < 9; ++j) {
      int i = tid + 256 * j;
      float v = kp[i];
      float gg = gp[i];
      kF[j] = key16_of(v * gg);
      kB[j] = key16_of(v * (1.0f - gg));
    }
    // ---- pass 0: high byte, per-wave histograms ----
#pragma unroll
    for (int w = 0; w < 4; ++w) {
      histF[w][tid] = 0;
      histB[w][tid] = 0;
    }
    __syncthreads();
#pragma unroll
    for (int j = 0; j < 9; ++j) {
      atomicAdd(&histF[wid][kF[j] >> 8], 1u);
      atomicAdd(&histB[wid][kB[j] >> 8], 1u);
    }
    __syncthreads();
    if (wid < 2) {
      unsigned(*hh)[256] = wid ? histB : histF;
      unsigned h0 = hh[0][4 * lane] + hh[1][4 * lane] + hh[2][4 * lane] + hh[3][4 * lane];
      unsigned h1 = hh[0][4 * lane + 1] + hh[1][4 * lane + 1] + hh[2][4 * lane + 1] +
                    hh[3][4 * lane + 1];
      unsigned h2 = hh[0][4 * lane + 2] + hh[1][4 * lane + 2] + hh[2][4 * lane + 2] +
                    hh[3][4 * lane + 2];
      unsigned h3 = hh[0][4 * lane + 3] + hh[1][4 * lane + 3] + hh[2][4 * lane + 3] +
                    hh[3][4 * lane + 3];
      unsigned x = h0 + h1 + h2 + h3;
#pragma unroll
      for (int d = 1; d < 64; d <<= 1) {
        unsigned y = __shfl_down(x, d, 64);
        if (lane + d < 64) x += y;
      }
      unsigned long long m = __ballot(x >= 256u);
      int tl = 63 - __clzll(m);
      if (lane == tl) {
        unsigned s1 = x - h0, s2 = s1 - h1, s3 = s2 - h2, s4 = s3 - h3;
        int jj;
        unsigned A;
        if (s3 >= 256u) { jj = 3; A = s4; }
        else if (s2 >= 256u) { jj = 2; A = s3; }
        else if (s1 >= 256u) { jj = 1; A = s2; }
        else { jj = 0; A = s1; }
        selT[wid] = 4 * tl + jj;
        selA[wid] = A;
      }
    }
    __syncthreads();
    const unsigned T0F = selT[0], gt0F = selA[0];
    const unsigned T0B = selT[1], gt0B = selA[1];
    const unsigned KF = 256u - gt0F, KB = 256u - gt0B;
    // ---- pass 1: low byte among elements matching high byte ----
    histF[0][tid] = 0;
    histB[0][tid] = 0;
    __syncthreads();
#pragma unroll
    for (int j = 0; j < 9; ++j) {
      if ((kF[j] >> 8) == T0F) atomicAdd(&histF[0][kF[j] & 0xFFu], 1u);
      if ((kB[j] >> 8) == T0B) atomicAdd(&histB[0][kB[j] & 0xFFu], 1u);
    }
    __syncthreads();
    if (wid < 2) {
      unsigned* h = wid ? histB[0] : histF[0];
      unsigned K = wid ? KB : KF;
      unsigned h0 = h[4 * lane], h1 = h[4 * lane + 1];
      unsigned h2 = h[4 * lane + 2], h3 = h[4 * lane + 3];
      unsigned x = h0 + h1 + h2 + h3;
#pragma unroll
      for (int d = 1; d < 64; d <<= 1) {
        unsigned y = __shfl_down(x, d, 64);
        if (lane + d < 64) x += y;
      }
      unsigned long long m = __ballot(x >= K);
      int tl = 63 - __clzll(m);
      if (lane == tl) {
        unsigned s1 = x - h0, s2 = s1 - h1, s3 = s2 - h2, s4 = s3 - h3;
        int jj;
        unsigned A;
        if (s3 >= K) { jj = 3; A = s4; }
        else if (s2 >= K) { jj = 2; A = s3; }
        else if (s1 >= K) { jj = 1; A = s2; }
        else { jj = 0; A = s1; }
        selT[wid] = 4 * tl + jj;
        selA[wid] = A;
      }
    }
    __syncthreads();
    const unsigned tF = (T0F << 8) | selT[0];
    const unsigned tB = (T0B << 8) | selT[1];
    const unsigned nGTF = gt0F + selA[0], needF = 256u - nGTF;
    const unsigned nGTB = gt0B + selA[1], needB = 256u - nGTB;
    if (tid == 0) { cntG[0] = 0; cntG[1] = 0; cntE[0] = 0; cntE[1] = 0; }
    __syncthreads();
#pragma unroll
    for (int j = 0; j < 9; ++j) {
      unsigned k = kF[j];
      if (k > tF) soutF[atomicAdd(&cntG[0], 1u)] = (ushort_t)k;
      else if (k == tF) {
        unsigned e = atomicAdd(&cntE[0], 1u);
        if (e < needF) soutF[nGTF + e] = (ushort_t)tF;
      }
      k = kB[j];
      if (k > tB) soutB[atomicAdd(&cntG[1], 1u)] = (ushort_t)k;
      else if (k == tB) {
        unsigned e = atomicAdd(&cntE[1], 1u);
        if (e < needB) soutB[nGTB + e] = (ushort_t)tB;
      }
    }
    __syncthreads();
    if (wid < 2) {
      ushort_t* sarr = wid ? soutB : soutF;
      for (int kk = 2; kk <= 256; kk <<= 1) {
        for (int j = kk >> 1; j > 0; j >>= 1) {
#pragma unroll
          for (int r = 0; r < 2; ++r) {
            int p = lane + r * 64;
            int t = (p & (j - 1)) | ((p & ~(j - 1)) << 1);
            int ixj = t | j;
            bool up = ((t & kk) == 0);
            ushort_t a = sarr[t], c = sarr[ixj];
            if (up ? (a > c) : (a < c)) { sarr[t] = c; sarr[ixj] = a; }
          }
          __builtin_amdgcn_wave_barrier();
        }
      }
    }
    __syncthreads();
    size_t base = ((size_t)(b * 2304 + yx)) * 1312;
    xcat[base + 256 + tid] = un_key16((unsigned)soutF[255 - tid]);
    xcat[base + 512 + tid] = un_key16((unsigned)soutB[255 - tid]);
  } else {
    // ================= LOCAL task (2 pixels, one wave per (pixel,F/B)) =================
    const int bl = g / 3;
    const int pix = bl * 2 + (wid >> 1);
    const int fb = wid & 1;
    const int b = pix / 2304;
    const int yx = pix - b * 2304;
    const int y = yx / 48, x = yx - y * 48;
    const ushort_t* kp = klpT16 + (size_t)pix * 320;
    float v8[8];
#pragma unroll
    for (int r = 0; r < 8; ++r) {
      int i = r * 64 + lane;
      float vv = -INFINITY;
      if (i < 289) {
        int dy = i / 17, dx = i - dy * 17;
        int sy = y + dy - 8, sx = x + dx - 8;
        float pv = 0.f;
        if (sy >= 0 && sy < 48 && sx >= 0 && sx < 48)
          pv = lm[(size_t)b * 2304 + sy * 48 + sx];
        float v = h2f(kp[i]);
        vv = v * (fb ? (1.0f - pv) : pv);
      }
      v8[r] = vv;
    }
    for (int k = 2; k <= 512; k <<= 1) {
      for (int j = k >> 1; j > 0; j >>= 1) {
        if (j >= 64) {
          const int jr = j >> 6;
#pragma unroll
          for (int r = 0; r < 8; ++r) {
            if ((r & jr) == 0) {
              const int rp = r | jr;
              bool up = (((unsigned)(r * 64) & (unsigned)k) == 0);
              float a = v8[r], c = v8[rp];
              if (up) {
                v8[r] = fminf(a, c); v8[rp] = fmaxf(a, c);
              } else {
                v8[r] = fmaxf(a, c); v8[rp] = fminf(a, c);
              }
            }
          }
        } else {
          bool lower = ((lane & j) == 0);
#pragma unroll
          for (int r = 0; r < 8; ++r) {
            float p = __shfl_xor(v8[r], j, 64);
            bool up = (((unsigned)(r * 64 + lane) & (unsigned)k) == 0);
            bool takeMin = (lower == up);
            v8[r] = takeMin ? fminf(v8[r], p) : fmaxf(v8[r], p);
          }
        }
      }
    }
    size_t base = (size_t)pix * 1312 + (fb ? 1024 : 768);
#pragma unroll
    for (int r = 4; r < 8; ++r) {
      int t = 511 - (r * 64 + lane);
      xcat[base + t] = f2h(v8[r]);
    }
  }
}

// ===== pm channel + zero pad channels of xcat (fp16) =====
__global__ __launch_bounds__(TPB) void pm_pad_kernel(const float* __restrict__ lm,
                                                     ushort_t* __restrict__ xcat) {
  int idx = blockIdx.x * TPB + threadIdx.x;
  if (idx >= 2 * 2304 * 32) return;
  int ch = idx & 31;
  int r = idx >> 5;
  xcat[(size_t)r * 1312 + 1280 + ch] = (ch == 0) ? f2h(lm[r]) : (ushort_t)0;
}

// ===== mega weight preconvert: all convs, single fp16 =====
struct WallDesc {
  const float* src[13];
  int CinW[13], CIP[13], CoutPad[13], CoutReal[13];
  unsigned start[14];
  int n;
};
__global__ __launch_bounds__(TPB) void wconv_all_kernel(WallDesc D, ushort_t* __restrict__ whi,
                                                        int total) {
  int i = blockIdx.x * TPB + threadIdx.x;
  if (i >= total) return;
  int k = 0;
  while (k + 1 < D.n && (unsigned)i >= D.start[k + 1]) ++k;
  int j = i - D.start[k];
  int e = j & 7;
  int t = j >> 3;
  int l16 = t & 15; t >>= 4;
  int h4 = t & 3; t >>= 2;
  int NCOG = D.CoutPad[k] >> 4;
  int cog = t % NCOG; t /= NCOG;
  int kykx = t % 9;
  int chunk = t / 9;
  int co = cog * 16 + l16;
  int ci = chunk * 32 + h4 * 8 + e;
  float v = 0.f;
  if (ci < D.CinW[k] && co < D.CoutReal[k])
    v = D.src[k][((size_t)co * D.CinW[k] + ci) * 9 + kykx];
  whi[i] = f2h(v);
}

// ===== apply norm(+res) to an 8-channel fp16 vector (used by fused staging) =====
// NORM: 1 = relu((x-m)*i); 2 = +fp16 res; 3 = +fp32 res
template <int NORM>
__device__ __forceinline__ uint4 norm8(uint4 v, const float* __restrict__ nmean,
                                       const float* __restrict__ ninv,
                                       const void* __restrict__ nres, size_t mb,
                                       size_t pxoff) {
  float f[8];
  f[0] = h2f((ushort_t)(v.x & 0xffff)); f[1] = h2f((ushort_t)(v.x >> 16));
  f[2] = h2f((ushort_t)(v.y & 0xffff)); f[3] = h2f((ushort_t)(v.y >> 16));
  f[4] = h2f((ushort_t)(v.z & 0xffff)); f[5] = h2f((ushort_t)(v.z >> 16));
  f[6] = h2f((ushort_t)(v.w & 0xffff)); f[7] = h2f((ushort_t)(v.w >> 16));
  float4 m0 = *(const float4*)(nmean + mb);
  float4 m1 = *(const float4*)(nmean + mb + 4);
  float4 i0 = *(const float4*)(ninv + mb);
  float4 i1 = *(const float4*)(ninv + mb + 4);
  float o[8];
  o[0] = fmaxf((f[0] - m0.x) * i0.x, 0.f);
  o[1] = fmaxf((f[1] - m0.y) * i0.y, 0.f);
  o[2] = fmaxf((f[2] - m0.z) * i0.z, 0.f);
  o[3] = fmaxf((f[3] - m0.w) * i0.w, 0.f);
  o[4] = fmaxf((f[4] - m1.x) * i1.x, 0.f);
  o[5] = fmaxf((f[5] - m1.y) * i1.y, 0.f);
  o[6] = fmaxf((f[6] - m1.z) * i1.z, 0.f);
  o[7] = fmaxf((f[7] - m1.w) * i1.w, 0.f);
  if (NORM == 2) {
    uint4 rv = *(const uint4*)((const ushort_t*)nres + pxoff);
    o[0] += h2f((ushort_t)(rv.x & 0xffff)); o[1] += h2f((ushort_t)(rv.x >> 16));
    o[2] += h2f((ushort_t)(rv.y & 0xffff)); o[3] += h2f((ushort_t)(rv.y >> 16));
    o[4] += h2f((ushort_t)(rv.z & 0xffff)); o[5] += h2f((ushort_t)(rv.z >> 16));
    o[6] += h2f((ushort_t)(rv.w & 0xffff)); o[7] += h2f((ushort_t)(rv.w >> 16));
  } else if (NORM == 3) {
    const float* rp = (const float*)nres + pxoff;
    float4 r0 = *(const float4*)rp;
    float4 r1 = *(const float4*)(rp + 4);
    o[0] += r0.x; o[1] += r0.y; o[2] += r0.z; o[3] += r0.w;
    o[4] += r1.x; o[5] += r1.y; o[6] += r1.z; o[7] += r1.w;
  }
  uint4 out;
  out.x = (unsigned)f2h(o[0]) | ((unsigned)f2h(o[1]) << 16);
  out.y = (unsigned)f2h(o[2]) | ((unsigned)f2h(o[3]) << 16);
  out.z = (unsigned)f2h(o[4]) | ((unsigned)f2h(o[5]) << 16);
  out.w = (unsigned)f2h(o[6]) | ((unsigned)f2h(o[7]) << 16);
  return out;
}

// ===== MFMA implicit-GEMM 3x3 conv, fp16 NHWC act (raw), single fp16 weights =====
// GEOM 0: tile 16x8, 4 waves = 2co x 2px, MB=MFR*32. GEOM 1: tile 8x8, MB=64, MFR=1.
// NORM: 0 none; 1 norm; 2 norm+fp16res; 3 norm+fp32res;
//       5 bilinear(src) upsample (src dims hin,win, scale rs).
// STAT=1 (S==1): per-tile channel sum/sumsq of STORED outputs.
// Split-K partials stored as packed fp16.
template <int MFR, int ACT, int STAT, int GEOM, int NORM>
__global__ __launch_bounds__(TPB) void conv_mfma_kernel(
    const ushort_t* __restrict__ in, const ushort_t* __restrict__ whi,
    const float* __restrict__ bias,
    ushort_t* __restrict__ outh, float* __restrict__ outf, ushort_t* __restrict__ partial,
    float* __restrict__ stat, int ntiles,
    const float* __restrict__ nmean, const float* __restrict__ ninv,
    const void* __restrict__ nres,
    int hin, int win, float rs,
    int CIP, int Cout, int H, int W, int S, int ci_per_s) {
  const int NPIX = (GEOM == 1) ? 100 : 180;
  const int PITCH = 10;
  __shared__ uint4 sB[(GEOM == 1) ? 800 : 1440];
  const int MB = (GEOM == 1) ? 64 : MFR * 32;
  const int tid = threadIdx.x;
  const int lane = tid & 63;
  const int lo16 = lane & 15, hi4 = lane >> 4;
  const int wid = tid >> 6;
  const int wco = (GEOM == 1) ? wid : (wid & 1);
  const int wpx = (GEOM == 1) ? 0 : (wid >> 1);
  const int tilesX = W >> 3;
  const int tx0 = (blockIdx.x % tilesX) << 3;
  const int ty0 = (blockIdx.x / tilesX) << ((GEOM == 1) ? 3 : 4);
  const int s = blockIdx.y % S;
  const int co0 = (blockIdx.y / S) * MB;
  const int b = blockIdx.z;
  const int NCOG = Cout >> 4;
  const size_t HW = (size_t)H * W;
  const ushort_t* inb = in + (size_t)b * HW * CIP;
  const ushort_t* srcb = in + (size_t)b * hin * win * CIP;  // for NORM==5
  int ci_begin = s * ci_per_s;
  int ci_end = ci_begin + ci_per_s;
  if (ci_end > CIP) ci_end = CIP;
  f4 acc[MFR][4];
#pragma unroll
  for (int m = 0; m < MFR; ++m)
#pragma unroll
    for (int n = 0; n < 4; ++n) acc[m][n] = (f4){0.f, 0.f, 0.f, 0.f};

  for (int ci0 = ci_begin; ci0 < ci_end; ci0 += 64) {
    const bool has2 = (ci0 + 32 < ci_end);
    __syncthreads();
#pragma unroll
    for (int it = 0; it < 6; ++it) {
      int u = it * TPB + tid;
      if (u < NPIX * 8) {
        int q4 = u / NPIX;
        int pix = u - q4 * NPIX;
        int prow = pix / PITCH, pcol = pix - prow * PITCH;
        int gy = ty0 - 1 + prow, gx = tx0 - 1 + pcol;
        int ci = ci0 + q4 * 8;
        bool inbp = (ci < CIP && gy >= 0 && gy < H && gx >= 0 && gx < W);
        uint4 v = {0u, 0u, 0u, 0u};
        if (inbp) {
          if (NORM <= 3) {
            v = *(const uint4*)(inb + ((size_t)gy * W + gx) * CIP + ci);
            if (NORM != 0) {
              size_t mb = (size_t)b * CIP + ci;
              size_t pxoff = ((size_t)b * HW + (size_t)gy * W + gx) * CIP + ci;
              v = norm8<NORM>(v, nmean, ninv, nres, mb, pxoff);
            }
          } else {
            float ys = gy * rs, xs = gx * rs;
            int y0 = (int)floorf(ys);
            if (y0 > hin - 1) y0 = hin - 1;
            int x0 = (int)floorf(xs);
            if (x0 > win - 1) x0 = win - 1;
            int y1 = y0 + 1 < hin ? y0 + 1 : hin - 1;
            int x1 = x0 + 1 < win ? x0 + 1 : win - 1;
            float wy = ys - (float)y0, wx = xs - (float)x0;
            uint4 s00 = *(const uint4*)(srcb + ((size_t)y0 * win + x0) * CIP + ci);
            uint4 s01 = *(const uint4*)(srcb + ((size_t)y0 * win + x1) * CIP + ci);
            uint4 s10 = *(const uint4*)(srcb + ((size_t)y1 * win + x0) * CIP + ci);
            uint4 s11 = *(const uint4*)(srcb + ((size_t)y1 * win + x1) * CIP + ci);
            float w00 = (1.f - wy) * (1.f - wx), w01 = (1.f - wy) * wx;
            float w10 = wy * (1.f - wx), w11 = wy * wx;
            union U8 { uint4 q; ushort_t sv[8]; };
            U8 u00, u01, u10, u11, uo;
            u00.q = s00; u01.q = s01; u10.q = s10; u11.q = s11;
#pragma unroll
            for (int k8 = 0; k8 < 8; ++k8) {
              float val = h2f(u00.sv[k8]) * w00 + h2f(u01.sv[k8]) * w01 +
                          h2f(u10.sv[k8]) * w10 + h2f(u11.sv[k8]) * w11;
              uo.sv[k8] = f2h(val);
            }
            v = uo.q;
          }
        }
        sB[q4 * NPIX + pix] = v;
      }
    }
    __syncthreads();
#pragma unroll
    for (int h = 0; h < 2; ++h) {
      if (h == 1 && !has2) continue;
      const int chunkIdx = (ci0 >> 5) + h;
#pragma unroll
      for (int ky = 0; ky < 3; ++ky) {
#pragma unroll
        for (int kx = 0; kx < 3; ++kx) {
          const int kykx = ky * 3 + kx;
          h8 ah[MFR];
#pragma unroll
          for (int m = 0; m < MFR; ++m) {
            int cog = (co0 + wco * (GEOM == 1 ? 16 : (MB / 2)) + m * 16) >> 4;
            size_t woff = (((size_t)chunkIdx * 9 + kykx) * NCOG + cog) * 512 + (size_t)lane * 8;
            ah[m] = *(const h8*)(whi + woff);
          }
          h8 bf[4];
#pragma unroll
          for (int n = 0; n < 4; ++n) {
            int pix = (wpx * 8 + n * 2 + (lo16 >> 3) + ky) * PITCH + (lo16 & 7) + kx;
            union { uint4 q; h8 v; } ub;
            ub.q = sB[(h * 4 + hi4) * NPIX + pix];
            bf[n] = ub.v;
          }
#pragma unroll
          for (int m = 0; m < MFR; ++m)
#pragma unroll
            for (int n = 0; n < 4; ++n)
              acc[m][n] = __builtin_amdgcn_mfma_f32_16x16x32_f16(ah[m], bf[n], acc[m][n], 0, 0, 0);
        }
      }
    }
  }

#pragma unroll
  for (int m = 0; m < MFR; ++m) {
#pragma unroll
    for (int n = 0; n < 4; ++n) {
      int py = ty0 + wpx * 8 + n * 2 + (lo16 >> 3);
      int pxx = tx0 + (lo16 & 7);
      int co_r0 = co0 + wco * (GEOM == 1 ? 16 : (MB / 2)) + m * 16 + hi4 * 4;
      if (ACT == 1) {
        if (wco == 0 && m == 0 && hi4 == 0) {
          float v = acc[0][n][0] + bias[0];
          outf[(size_t)b * HW + (size_t)py * W + pxx] = 1.0f / (1.0f + expf(-v));
        }
      } else if (S == 1) {
        float4 bv = *(const float4*)(bias + co_r0);
        unsigned w0 = (unsigned)f2h(acc[m][n][0] + bv.x) |
                      ((unsigned)f2h(acc[m][n][1] + bv.y) << 16);
        unsigned w1 = (unsigned)f2h(acc[m][n][2] + bv.z) |
                      ((unsigned)f2h(acc[m][n][3] + bv.w) << 16);
        uint2 o = {w0, w1};
        *(uint2*)(outh + (((size_t)b * HW + (size_t)py * W + pxx) * Cout + co_r0)) = o;
        if (STAT) {
          acc[m][n][0] = h2f((ushort_t)(w0 & 0xffff));
          acc[m][n][1] = h2f((ushort_t)(w0 >> 16));
          acc[m][n][2] = h2f((ushort_t)(w1 & 0xffff));
          acc[m][n][3] = h2f((ushort_t)(w1 >> 16));
        }
      } else {
        uint2 o;
        o.x = (unsigned)f2h(acc[m][n][0]) | ((unsigned)f2h(acc[m][n][1]) << 16);
        o.y = (unsigned)f2h(acc[m][n][2]) | ((unsigned)f2h(acc[m][n][3]) << 16);
        *(uint2*)(partial + (((size_t)(s * 2 + b) * HW + (size_t)py * W + pxx) * Cout + co_r0)) = o;
      }
    }
  }

  if (STAT) {
    __syncthreads();
    f4* lredS = (f4*)sB;
    f4* lredQ = lredS + 32;
    if (GEOM == 1) {
      f4 sv = acc[0][0] + acc[0][1] + acc[0][2] + acc[0][3];
      f4 qv = acc[0][0] * acc[0][0] + acc[0][1] * acc[0][1] + acc[0][2] * acc[0][2] +
              acc[0][3] * acc[0][3];
#pragma unroll
      for (int off = 1; off < 16; off <<= 1) {
#pragma unroll
        for (int kq = 0; kq < 4; ++kq) {
          sv[kq] += __shfl_xor(sv[kq], off, 64);
          qv[kq] += __shfl_xor(qv[kq], off, 64);
        }
      }
      if (lo16 == 0) {
        lredS[wid * 4 + hi4] = sv;
        lredQ[wid * 4 + hi4] = qv;
      }
      __syncthreads();
      if (tid < 16) {
        int widT = tid >> 2, h4T = tid & 3;
        int c = co0 + widT * 16 + h4T * 4;
        size_t sbase = ((size_t)b * ntiles + blockIdx.x) * (size_t)(Cout * 2);
        *(f4*)(stat + sbase + c) = lredS[tid];
        *(f4*)(stat + sbase + Cout + c) = lredQ[tid];
      }
    } else {
#pragma unroll
      for (int m = 0; m < MFR; ++m) {
        f4 sv = acc[m][0] + acc[m][1] + acc[m][2] + acc[m][3];
        f4 qv = acc[m][0] * acc[m][0] + acc[m][1] * acc[m][1] + acc[m][2] * acc[m][2] +
                acc[m][3] * acc[m][3];
#pragma unroll
        for (int off = 1; off < 16; off <<= 1) {
#pragma unroll
          for (int kq = 0; kq < 4; ++kq) {
            sv[kq] += __shfl_xor(sv[kq], off, 64);
            qv[kq] += __shfl_xor(qv[kq], off, 64);
          }
        }
        if (lo16 == 0) {
          lredS[(wid * MFR + m) * 4 + hi4] = sv;
          lredQ[(wid * MFR + m) * 4 + hi4] = qv;
        }
      }
      __syncthreads();
      if (tid < 2 * MFR * 4) {
        int wcoT = tid / (MFR * 4);
        int r = tid % (MFR * 4);
        int mT = r / 4;
        int h4T = r % 4;
        f4 sv = lredS[((wcoT)*MFR + mT) * 4 + h4T] + lredS[((wcoT + 2) * MFR + mT) * 4 + h4T];
        f4 qv = lredQ[((wcoT)*MFR + mT) * 4 + h4T] + lredQ[((wcoT + 2) * MFR + mT) * 4 + h4T];
        int c = co0 + wcoT * (MB / 2) + mT * 16 + h4T * 4;
        size_t sbase = ((size_t)b * ntiles + blockIdx.x) * (size_t)(Cout * 2);
        *(f4*)(stat + sbase + c) = sv;
        *(f4*)(stat + sbase + Cout + c) = qv;
      }
    }
  }
}

// ===== scalar pred head: norm(zB raw) -> conv3x3 64->1 + sigmoid =====
__global__ __launch_bounds__(TPB) void pred_kernel(const ushort_t* __restrict__ in,
                                                   const float* __restrict__ w,
                                                   const float* __restrict__ bias,
                                                   const float* __restrict__ nmean,
                                                   const float* __restrict__ ninv,
                                                   float* __restrict__ outp) {
  __shared__ uint4 hal[324 * 9];
  __shared__ float wl[576];
  const int tid = threadIdx.x;
  const int tx0 = (blockIdx.x % 12) * 16;
  const int ty0 = (blockIdx.x / 12) * 16;
  const int b = blockIdx.y;
  const ushort_t* inb = in + (size_t)b * 36864 * 64;
  for (int u = tid; u < 576; u += TPB) {
    int ci = u & 63, kk = u >> 6;
    wl[u] = w[(size_t)ci * 9 + kk];
  }
  for (int u = tid; u < 2592; u += TPB) {
    int px = u >> 3, q4 = u & 7;
    int r = px / 18, c = px - r * 18;
    int gy = ty0 - 1 + r, gx = tx0 - 1 + c;
    uint4 v = {0u, 0u, 0u, 0u};
    if (gy >= 0 && gy < 192 && gx >= 0 && gx < 192) {
      v = *(const uint4*)(inb + ((size_t)gy * 192 + gx) * 64 + q4 * 8);
      v = norm8<1>(v, nmean, ninv, nullptr, (size_t)b * 64 + q4 * 8, 0);
    }
    hal[px * 9 + q4] = v;
  }
  __syncthreads();
  const int ty = tid >> 4, tx = tid & 15;
  float acc = bias[0];
#pragma unroll
  for (int ky = 0; ky < 3; ++ky) {
#pragma unroll
    for (int kx = 0; kx < 3; ++kx) {
      int base = ((ty + ky) * 18 + tx + kx) * 9;
      const float* wp = &wl[(ky * 3 + kx) * 64];
#pragma unroll
      for (int q = 0; q < 8; ++q) {
        uint4 v = hal[base + q];
        const float* w8 = wp + q * 8;
        acc = fmaf(h2f((ushort_t)(v.x & 0xffff)), w8[0], acc);
        acc = fmaf(h2f((ushort_t)(v.x >> 16)), w8[1], acc);
        acc = fmaf(h2f((ushort_t)(v.y & 0xffff)), w8[2], acc);
        acc = fmaf(h2f((ushort_t)(v.y >> 16)), w8[3], acc);
        acc = fmaf(h2f((ushort_t)(v.z & 0xffff)), w8[4], acc);
        acc = fmaf(h2f((ushort_t)(v.z >> 16)), w8[5], acc);
        acc = fmaf(h2f((ushort_t)(v.w & 0xffff)), w8[6], acc);
        acc = fmaf(h2f((ushort_t)(v.w >> 16)), w8[7], acc);
      }
    }
  }
  outp[(size_t)b * 36864 + (size_t)(ty0 + ty) * 192 + (tx0 + tx)] =
      1.0f / (1.0f + expf(-acc));
}

// ===== split-K reduce + bias -> fp16 NHWC (fp16 packed partials) =====
template <int STAT>
__global__ __launch_bounds__(TPB) void reduce_nhwc_kernel(const ushort_t* __restrict__ partial,
                                                          const float* __restrict__ bias,
                                                          ushort_t* __restrict__ outh,
                                                          float* __restrict__ stat, int bpb,
                                                          int S, int Cout, int HW, int total4) {
  int i = blockIdx.x * TPB + threadIdx.x;
  float4 accv = {0.f, 0.f, 0.f, 0.f};
  unsigned w0 = 0, w1 = 0;
  int e = i * 4;
  int CHW = Cout * HW;
  if (i < total4) {
    int b = e / CHW;
    int rem = e - b * CHW;
    int co = e % Cout;
    for (int ss = 0; ss < S; ++ss) {
      const uint2 t2 = *(const uint2*)(partial + (size_t)(ss * 2 + b) * CHW + rem);
      accv.x += h2f((ushort_t)(t2.x & 0xffff));
      accv.y += h2f((ushort_t)(t2.x >> 16));
      accv.z += h2f((ushort_t)(t2.y & 0xffff));
      accv.w += h2f((ushort_t)(t2.y >> 16));
    }
    float4 bv = *(const float4*)(bias + co);
    w0 = (unsigned)f2h(accv.x + bv.x) | ((unsigned)f2h(accv.y + bv.y) << 16);
    w1 = (unsigned)f2h(accv.z + bv.z) | ((unsigned)f2h(accv.w + bv.w) << 16);
    uint2 o = {w0, w1};
    *(uint2*)(outh + (size_t)b * CHW + rem) = o;
  }
  if (STAT) {
    __shared__ f4 ls[4][16], lq[4][16];
    const int tid = threadIdx.x;
    const int lane = tid & 63, wv = tid >> 6;
    f4 r;
    r[0] = h2f((ushort_t)(w0 & 0xffff));
    r[1] = h2f((ushort_t)(w0 >> 16));
    r[2] = h2f((ushort_t)(w1 & 0xffff));
    r[3] = h2f((ushort_t)(w1 >> 16));
    f4 sv = r;
    f4 qv = r * r;
#pragma unroll
    for (int kq = 0; kq < 4; ++kq) {
      sv[kq] += __shfl_down(sv[kq], 16, 64);
      qv[kq] += __shfl_down(qv[kq], 16, 64);
      sv[kq] += __shfl_down(sv[kq], 32, 64);
      qv[kq] += __shfl_down(qv[kq], 32, 64);
    }
    if (lane < 16) {
      ls[wv][lane] = sv;
      lq[wv][lane] = qv;
    }
    __syncthreads();
    if (tid < 16) {
      f4 S4 = ls[0][tid] + ls[1][tid] + ls[2][tid] + ls[3][tid];
      f4 Q4 = lq[0][tid] + lq[1][tid] + lq[2][tid] + lq[3][tid];
      int b = (blockIdx.x * (TPB * 4)) / CHW;
      int tblk = blockIdx.x - b * bpb;
      int c = tid * 4;
      size_t sbase = ((size_t)b * bpb + tblk) * (size_t)(Cout * 2);
      *(f4*)(stat + sbase + c) = S4;
      *(f4*)(stat + sbase + Cout + c) = Q4;
    }
  }
}

// ===== InstanceNorm stats (fp16 NHWC path, for non-fused inorms) =====
__global__ __launch_bounds__(TPB) void in_stats_kernel(const ushort_t* __restrict__ x,
                                                       float* __restrict__ stat, int N, int C) {
  __shared__ float ls[4][64], lq[4][64];
  int CG = C >> 6;
  int b = blockIdx.x / CG, cg = blockIdx.x % CG;
  int slice = blockIdx.y;
  int c = threadIdx.x & 63, p = threadIdx.x >> 6;
  int cnt = N >> 6;
  int base = slice * cnt;
  float s = 0.f, q = 0.f;
  const ushort_t* xp = x + ((size_t)b * N) * C + cg * 64 + c;
  for (int px = base + p; px < base + cnt; px += 4) {
    float v = h2f(xp[(size_t)px * C]);
    s += v;
    q = fmaf(v, v, q);
  }
  ls[p][c] = s;
  lq[p][c] = q;
  __syncthreads();
  if (threadIdx.x < 64) {
    float S = ls[0][threadIdx.x] + ls[1][threadIdx.x] + ls[2][threadIdx.x] + ls[3][threadIdx.x];
    float Q = lq[0][threadIdx.x] + lq[1][threadIdx.x] + lq[2][threadIdx.x] + lq[3][threadIdx.x];
    int Ctot = 2 * C;
    int idx = b * C + cg * 64 + threadIdx.x;
    stat[(size_t)(slice * Ctot + idx) * 2] = S;
    stat[(size_t)(slice * Ctot + idx) * 2 + 1] = Q;
  }
}

__global__ __launch_bounds__(TPB) void in_final_kernel(const float* __restrict__ stat,
                                                       float* __restrict__ mean,
                                                       float* __restrict__ inv, int N, int Ctot) {
  int idx = blockIdx.x * TPB + threadIdx.x;
  if (idx >= Ctot) return;
  float S = 0.f, Q = 0.f;
  for (int sl = 0; sl < 64; ++sl) {
    S += stat[(size_t)(sl * Ctot + idx) * 2];
    Q += stat[(size_t)(sl * Ctot + idx) * 2 + 1];
  }
  float m = S / (float)N;
  float var = Q / (float)N - m * m;
  if (var < 0.f) var = 0.f;
  mean[idx] = m;
  inv[idx] = 1.0f / sqrtf(var + 1e-5f);
}

// ===== finalize from per-tile stats: ONE BLOCK PER (b,c) =====
__global__ __launch_bounds__(TPB) void in_final_tiles_kernel(const float* __restrict__ stat,
                                                             float* __restrict__ mean,
                                                             float* __restrict__ inv, int N,
                                                             int C, int ntiles) {
  __shared__ float rs_[TPB], rq_[TPB];
  int idx = blockIdx.x;  // b*C + c
  int b = idx / C, c = idx % C;
  float S = 0.f, Q = 0.f;
  for (int t = threadIdx.x; t < ntiles; t += TPB) {
    size_t base = ((size_t)b * ntiles + t) * (size_t)(C * 2);
    S += stat[base + c];
    Q += stat[base + C + c];
  }
  rs_[threadIdx.x] = S;
  rq_[threadIdx.x] = Q;
  __syncthreads();
  for (int off = TPB / 2; off > 0; off >>= 1) {
    if (threadIdx.x < off) {
      rs_[threadIdx.x] += rs_[threadIdx.x + off];
      rq_[threadIdx.x] += rq_[threadIdx.x + off];
    }
    __syncthreads();
  }
  if (threadIdx.x == 0) {
    float ma = rs_[0] / (float)N;
    float var = rq_[0] / (float)N - ma * ma;
    if (var < 0.f) var = 0.f;
    mean[idx] = ma;
    inv[idx] = 1.0f / sqrtf(var + 1e-5f);
  }
}

// ===== bilinear resize align_corners, fp16 NHWC; NORM=1 normalizes samples first =====
template <int NORM>
__global__ __launch_bounds__(TPB) void resize4_kernel(const ushort_t* __restrict__ in,
                                                      ushort_t* __restrict__ out,
                                                      const float* __restrict__ nmean,
                                                      const float* __restrict__ ninv, int C,
                                                      int hin, int win, int Hout, int Wout,
                                                      float r, int total4) {
  for (int i = blockIdx.x * TPB + threadIdx.x; i < total4; i += gridDim.x * TPB) {
    int e = i * 4;
    int c = e % C;
    int t = e / C;
    int X = t % Wout;
    int t2 = t / Wout;
    int Y = t2 % Hout;
    int b = t2 / Hout;
    float ys = Y * r, xs = X * r;
    int y0 = (int)floorf(ys);
    if (y0 > hin - 1) y0 = hin - 1;
    int x0 = (int)floorf(xs);
    if (x0 > win - 1) x0 = win - 1;
    int y1 = y0 + 1 < hin ? y0 + 1 : hin - 1;
    int x1 = x0 + 1 < win ? x0 + 1 : win - 1;
    float wy = ys - (float)y0, wx = xs - (float)x0;
    const ushort_t* ip = in + ((size_t)b * hin * win) * C + c;
    uint2 a2 = *(const uint2*)(ip + ((size_t)y0 * win + x0) * C);
    uint2 b2 = *(const uint2*)(ip + ((size_t)y0 * win + x1) * C);
    uint2 c2 = *(const uint2*)(ip + ((size_t)y1 * win + x0) * C);
    uint2 d2 = *(const uint2*)(ip + ((size_t)y1 * win + x1) * C);
    float av[4], bv[4], cv[4], dv[4];
    av[0] = h2f((ushort_t)(a2.x & 0xffff)); av[1] = h2f((ushort_t)(a2.x >> 16));
    av[2] = h2f((ushort_t)(a2.y & 0xffff)); av[3] = h2f((ushort_t)(a2.y >> 16));
    bv[0] = h2f((ushort_t)(b2.x & 0xffff)); bv[1] = h2f((ushort_t)(b2.x >> 16));
    bv[2] = h2f((ushort_t)(b2.y & 0xffff)); bv[3] = h2f((ushort_t)(b2.y >> 16));
    cv[0] = h2f((ushort_t)(c2.x & 0xffff)); cv[1] = h2f((ushort_t)(c2.x >> 16));
    cv[2] = h2f((ushort_t)(c2.y & 0xffff)); cv[3] = h2f((ushort_t)(c2.y >> 16));
    dv[0] = h2f((ushort_t)(d2.x & 0xffff)); dv[1] = h2f((ushort_t)(d2.x >> 16));
    dv[2] = h2f((ushort_t)(d2.y & 0xffff)); dv[3] = h2f((ushort_t)(d2.y >> 16));
    if (NORM) {
      float4 m4 = *(const float4*)(nmean + (size_t)b * C + c);
      float4 i4 = *(const float4*)(ninv + (size_t)b * C + c);
      float mm[4] = {m4.x, m4.y, m4.z, m4.w};
      float ii[4] = {i4.x, i4.y, i4.z, i4.w};
#pragma unroll
      for (int k = 0; k < 4; ++k) {
        av[k] = fmaxf((av[k] - mm[k]) * ii[k], 0.f);
        bv[k] = fmaxf((bv[k] - mm[k]) * ii[k], 0.f);
        cv[k] = fmaxf((cv[k] - mm[k]) * ii[k], 0.f);
        dv[k] = fmaxf((dv[k] - mm[k]) * ii[k], 0.f);
      }
    }
    float w00 = (1.f - wy) * (1.f - wx), w01 = (1.f - wy) * wx;
    float w10 = wy * (1.f - wx), w11 = wy * wx;
    float o[4];
#pragma unroll
    for (int k = 0; k < 4; ++k)
      o[k] = av[k] * w00 + bv[k] * w01 + cv[k] * w10 + dv[k] * w11;
    uint2 ov;
    ov.x = (unsigned)f2h(o[0]) | ((unsigned)f2h(o[1]) << 16);
    ov.y = (unsigned)f2h(o[2]) | ((unsigned)f2h(o[3]) << 16);
    *(uint2*)(out + e) = ov;
  }
}

extern "C" void kernel_launch(void* const* d_in, const int* in_sizes, int n_in,
                              void* d_out, int out_size, void* d_ws, size_t ws_size,
                              hipStream_t stream) {
  (void)in_sizes; (void)n_in; (void)out_size;
  const float* p3 = (const float*)d_in[0];
  const float* p2 = (const float*)d_in[1];
  const float* p1 = (const float*)d_in[2];
  const float* kg1 = (const float*)d_in[3];
  const float* klp = (const float*)d_in[4];
  const float* key_mask = (const float*)d_in[5];
  const float* pre_mask = (const float*)d_in[6];
  const float* conv_top_w = (const float*)d_in[7];
  const float* conv_top_b = (const float*)d_in[8];
  const float* aic_top_w1 = (const float*)d_in[9];
  const float* aic_top_b1 = (const float*)d_in[10];
  const float* aic_top_w2 = (const float*)d_in[11];
  const float* aic_top_b2 = (const float*)d_in[12];
  const float* r1a_w1 = (const float*)d_in[13];
  const float* r1a_b1 = (const float*)d_in[14];
  const float* r1a_w2 = (const float*)d_in[15];
  const float* r1a_b2 = (const float*)d_in[16];
  const float* r1b_w1 = (const float*)d_in[17];
  const float* r1b_b1 = (const float*)d_in[18];
  const float* r1b_w2 = (const float*)d_in[19];
  const float* r1b_b2 = (const float*)d_in[20];
  const float* r2a_w1 = (const float*)d_in[21];
  const float* r2a_b1 = (const float*)d_in[22];
  const float* r2a_w2 = (const float*)d_in[23];
  const float* r2a_b2 = (const float*)d_in[24];
  const float* r2b_w1 = (const float*)d_in[25];
  const float* r2b_b1 = (const float*)d_in[26];
  const float* r2b_w2 = (const float*)d_in[27];
  const float* r2b_b2 = (const float*)d_in[28];
  const float* dec_w = (const float*)d_in[29];
  const float* dec_b = (const float*)d_in[30];
  const float* pred_w = (const float*)d_in[31];
  const float* pred_b = (const float*)d_in[32];
  float* outp = (float*)d_out;

  // workspace layout (float units)
  const size_t OFF_GM = 0;
  const size_t OFF_LM = 4608;
  const size_t OFF_STAT = 9216;       // 294912 f
  const size_t OFF_MEAN = 304128;     // 512
  const size_t OFF_INV = 304640;      // 512
  const size_t OFF_WB = 305152;       // 4,239,360 f window (fp16 weights use half)
  const size_t OFF_AH0 = 4544512;     // 3,022,848 f  xcat/y96
  const size_t OFF_AH1 = 7567360;     // 589,824 f    a0/h96/d96  (klpT16 pre-conv)
  const size_t OFF_AH2 = 8157184;     // 147,456 f    h48         (klpT16 tail)
  const size_t OFF_AH3 = 8304640;     // 589,824 f    a1
  const size_t OFF_AH4 = 8894464;     // 2,359,296 f  R1/zA   (kgT + PbufTop window)
  const size_t OFF_AH5 = 11253760;    // 2,359,296 f  R0/zB
  const size_t OFF_P1T = 13613056;    // 4,718,592 f  partials(fp16) / p1t
  const size_t OFF_P2T = 18331648;    // 1,179,648 f  p2t (fp16)
  const size_t TOTAL_F = 19511296;    // ~78 MB
  if (ws_size < TOTAL_F * sizeof(float)) return;

  float* ws = (float*)d_ws;
  float* gm = ws + OFF_GM;
  float* lm = ws + OFF_LM;
  float* statb = ws + OFF_STAT;
  float* meanb = ws + OFF_MEAN;
  float* invb = ws + OFF_INV;
  ushort_t* wbh = (ushort_t*)(ws + OFF_WB);
  ushort_t* xcat_h = (ushort_t*)(ws + OFF_AH0);
  ushort_t* y96_h = (ushort_t*)(ws + OFF_AH0);
  ushort_t* a0_h = (ushort_t*)(ws + OFF_AH1);
  ushort_t* h96_h = (ushort_t*)(ws + OFF_AH1);
  ushort_t* d96_h = (ushort_t*)(ws + OFF_AH1);
  ushort_t* h48_h = (ushort_t*)(ws + OFF_AH2);
  ushort_t* a1_h = (ushort_t*)(ws + OFF_AH3);
  ushort_t* R1_h = (ushort_t*)(ws + OFF_AH4);
  ushort_t* zA_h = (ushort_t*)(ws + OFF_AH4);
  ushort_t* R0_h = (ushort_t*)(ws + OFF_AH5);
  ushort_t* zB_h = (ushort_t*)(ws + OFF_AH5);
  ushort_t* Pbuf16 = (ushort_t*)(ws + OFF_P1T);     // fp16 partials (small convs)
  ushort_t* PbufTop16 = (ushort_t*)(ws + OFF_AH4);  // conv_top S=7 fp16 partials
  float* p1t = ws + OFF_P1T;
  ushort_t* p2t = (ushort_t*)(ws + OFF_P2T);
  float* kgT = ws + OFF_AH4;              // AH4..end window (pre-conv only)
  ushort_t* klpT16 = (ushort_t*)(ws + OFF_AH1);  // fp16, 1,474,560 sh = AH1+AH2 exactly

  // ---- mega weight conversion (single fp16) ----
  WallDesc D;
  const float* wsrc[13] = {conv_top_w, aic_top_w1, aic_top_w2, r1a_w1, r1a_w2, r1b_w1,
                           r1b_w2, dec_w, r2a_w1, r2a_w2, r2b_w1, r2b_w2, pred_w};
  const int wcin[13] = {1281, 256, 64, 256, 64, 256, 64, 256, 64, 64, 64, 64, 64};
  const int wcip[13] = {1312, 256, 64, 256, 64, 256, 64, 256, 64, 64, 64, 64, 64};
  const int wcop[13] = {256, 64, 256, 64, 256, 64, 256, 64, 64, 64, 64, 64, 64};
  const int wcor[13] = {256, 64, 256, 64, 256, 64, 256, 64, 64, 64, 64, 64, 1};
  unsigned cum = 0;
  unsigned woff[13];
  for (int k = 0; k < 13; ++k) {
    D.src[k] = wsrc[k];
    D.CinW[k] = wcin[k];
    D.CIP[k] = wcip[k];
    D.CoutPad[k] = wcop[k];
    D.CoutReal[k] = wcor[k];
    D.start[k] = cum;
    woff[k] = cum;
    cum += (unsigned)(wcop[k] * 9 * wcip[k]);
  }
  D.start[13] = cum;
  D.n = 13;
  wconv_all_kernel<<<(cum + TPB - 1) / TPB, TPB, 0, stream>>>(D, wbh, (int)cum);

  // ---- pooled masks, correlation transposes, fused top-k, xcat assembly ----
  pool8_kernel<<<(2 * 2304 + TPB - 1) / TPB, TPB, 0, stream>>>(key_mask, gm, 2 * 2304);
  pool8_kernel<<<(2 * 2304 + TPB - 1) / TPB, TPB, 0, stream>>>(pre_mask, lm, 2 * 2304);
  tposegh_kernel<<<dim3(36, 5, 2), TPB, 0, stream>>>(klp, klpT16, 289, 2304, 320);
  tposef_kernel<<<dim3(36, 36, 2), TPB, 0, stream>>>(kg1, kgT, 2304, 2304, 2304);
  topk_all_kernel<<<6912, TPB, 0, stream>>>(kgT, gm, klpT16, lm, xcat_h);
  tposeh_kernel<<<dim3(36, 4, 2), TPB, 0, stream>>>(p3, xcat_h, 256, 2304, 1312);
  pm_pad_kernel<<<(2 * 2304 * 32 + TPB - 1) / TPB, TPB, 0, stream>>>(lm, xcat_h);

  // geom: 0 = 16x8 tile (MB 64/128), 1 = 8x8 tile MB=64 MFR=1 (always STAT).
  // normMode: 0 none, 1 norm, 2 norm+fp16res, 3 norm+fp32res,
  //           5 bilinear(src)    [src dims hin x win, scale rsc]
  auto conv = [&](const ushort_t* src, int wk, const float* bb, ushort_t* dsth,
                  ushort_t* part, int CIP, int CoutPad, int H, int W, int S, int MB,
                  int geom, int redStat, int normMode, const void* res, int hin, int win,
                  float rsc) {
    const ushort_t* whiK = wbh + woff[wk];
    int chunks = CIP / 32;
    int cps = ((chunks + S - 1) / S) * 32;
    if (geom == 1) {
      int ntiles = (W / 8) * (H / 8);
      dim3 grid(ntiles, CoutPad / 64, 2);
      if (normMode == 1)
        conv_mfma_kernel<1, 0, 1, 1, 1><<<grid, TPB, 0, stream>>>(
            src, whiK, bb, dsth, nullptr, nullptr, statb, ntiles, meanb, invb, res,
            hin, win, rsc, CIP, CoutPad, H, W, 1, cps);
      else if (normMode == 3)
        conv_mfma_kernel<1, 0, 1, 1, 3><<<grid, TPB, 0, stream>>>(
            src, whiK, bb, dsth, nullptr, nullptr, statb, ntiles, meanb, invb, res,
            hin, win, rsc, CIP, CoutPad, H, W, 1, cps);
      else if (normMode == 5)
        conv_mfma_kernel<1, 0, 1, 1, 5><<<grid, TPB, 0, stream>>>(
            src, whiK, bb, dsth, nullptr, nullptr, statb, ntiles, meanb, invb, res,
            hin, win, rsc, CIP, CoutPad, H, W, 1, cps);
      else
        conv_mfma_kernel<1, 0, 1, 1, 0><<<grid, TPB, 0, stream>>>(
            src, whiK, bb, dsth, nullptr, nullptr, statb, ntiles, meanb, invb, res,
            hin, win, rsc, CIP, CoutPad, H, W, 1, cps);
      return;
    }
    int ntiles = (W / 8) * (H / 16);
    dim3 grid(ntiles, (CoutPad / MB) * S, 2);
    if (MB == 128)
      conv_mfma_kernel<4, 0, 0, 0, 0><<<grid, TPB, 0, stream>>>(
          src, whiK, bb, dsth, nullptr, part, nullptr, 0, meanb, invb, res, hin, win,
          rsc, CIP, CoutPad, H, W, S, cps);
    else if (normMode == 1)
      conv_mfma_kernel<2, 0, 0, 0, 1><<<grid, TPB, 0, stream>>>(
          src, whiK, bb, dsth, nullptr, part, nullptr, 0, meanb, invb, res, hin, win,
          rsc, CIP, CoutPad, H, W, S, cps);
    else if (normMode == 2)
      conv_mfma_kernel<2, 0, 0, 0, 2><<<grid, TPB, 0, stream>>>(
          src, whiK, bb, dsth, nullptr, part, nullptr, 0, meanb, invb, res, hin, win,
          rsc, CIP, CoutPad, H, W, S, cps);
    else
      conv_mfma_kernel<2, 0, 0, 0, 0><<<grid, TPB, 0, stream>>>(
          src, whiK, bb, dsth, nullptr, part, nullptr, 0, meanb, invb, res, hin, win,
          rsc, CIP, CoutPad, H, W, S, cps);
    if (S > 1) {
      int HW = H * W;
      int total4 = 2 * CoutPad * HW / 4;
      int nblk = (total4 + TPB - 1) / TPB;
      int bpb = (CoutPad * HW) / (TPB * 4);
      if (redStat)
        reduce_nhwc_kernel<1><<<nblk, TPB, 0, stream>>>(part, bb, dsth, statb, bpb, S,
                                                        CoutPad, HW, total4);
      else
        reduce_nhwc_kernel<0><<<nblk, TPB, 0, stream>>>(part, bb, dsth, nullptr, 0, S,
                                                        CoutPad, HW, total4);
    }
  };
  auto stats_plain = [&](ushort_t* x, int C, int N) {
    dim3 g1(2 * (C / 64), 64);
    in_stats_kernel<<<g1, TPB, 0, stream>>>(x, statb, N, C);
    int Ctot = 2 * C;
    in_final_kernel<<<(Ctot + TPB - 1) / TPB, TPB, 0, stream>>>(statb, meanb, invb, N, Ctot);
  };
  auto stats_tiles = [&](int C, int N, int ntiles) {
    in_final_tiles_kernel<<<2 * C, TPB, 0, stream>>>(statb, meanb, invb, N, C, ntiles);
  };

  // ---- top fuse @48 ----
  conv(xcat_h, 0, conv_top_b, a0_h, PbufTop16, 1312, 256, 48, 48, 7, 128, 0, 0, 0, nullptr,
       48, 48, 1.f);
  conv(a0_h, 1, aic_top_b1, h48_h, Pbuf16, 256, 64, 48, 48, 8, 64, 0, 1, 0, nullptr, 48, 48,
       1.f);
  stats_tiles(64, 2304, 144);                                     // h48 stats -> meanb
  conv(h48_h, 2, aic_top_b2, a1_h, Pbuf16, 64, 256, 48, 48, 2, 64, 0, 0, 1, nullptr, 48, 48,
       1.f);
  stats_plain(a1_h, 256, 2304);                                   // a1 stats -> meanb

  // ---- 48 -> 96: separate resize (normalizes a1 on the fly) -> y96 ----
  {
    int total4 = 2 * 96 * 96 * 256 / 4;
    int g = (total4 + TPB - 1) / TPB; if (g > 4096) g = 4096;
    resize4_kernel<1><<<g, TPB, 0, stream>>>(a1_h, y96_h, meanb, invb, 256, 48, 48, 96, 96,
                                             47.f / 95.f, total4);
  }
  conv(y96_h, 3, r1a_b1, h96_h, Pbuf16, 256, 64, 96, 96, 4, 64, 0, 1, 0, nullptr, 96, 96,
       1.f);
  tposeh_kernel<<<dim3(144, 4, 2), TPB, 0, stream>>>(p2, p2t, 256, 9216, 256);
  stats_tiles(64, 9216, 576);                                     // h96 stats -> meanb
  conv(h96_h, 4, r1a_b2, R1_h, nullptr, 64, 256, 96, 96, 1, 64, 1, 0, 1, nullptr, 96, 96,
       1.f);
  stats_tiles(256, 9216, 144);                                    // R1 stats -> meanb
  conv(R1_h, 5, r1b_b1, h96_h, Pbuf16, 256, 64, 96, 96, 4, 64, 0, 1, 2, p2t, 96, 96, 1.f);
  stats_tiles(64, 9216, 576);                                     // h96 stats -> meanb
  conv(h96_h, 6, r1b_b2, R0_h, nullptr, 64, 256, 96, 96, 1, 64, 1, 0, 1, nullptr, 96, 96,
       1.f);
  stats_tiles(256, 9216, 144);                                    // R0 stats -> meanb
  conv(R0_h, 7, dec_b, d96_h, Pbuf16, 256, 64, 96, 96, 4, 64, 0, 0, 1, nullptr, 96, 96,
       1.f);
  tposef_kernel<<<dim3(576, 1, 2), TPB, 0, stream>>>(p1, p1t, 64, 36864, 64);

  // ---- 96 -> 192: r2a_w1 reads bilinear(d96) directly (fused resize) ----
  conv(d96_h, 8, r2a_b1, zA_h, nullptr, 64, 64, 192, 192, 1, 64, 1, 0, 5, nullptr, 96, 96,
       95.f / 191.f);
  stats_tiles(64, 36864, 576);                                    // zA stats -> meanb
  conv(zA_h, 9, r2a_b2, zB_h, nullptr, 64, 64, 192, 192, 1, 64, 1, 0, 1, nullptr, 192, 192,
       1.f);
  stats_tiles(64, 36864, 576);                                    // zB stats -> meanb
  conv(zB_h, 10, r2b_b1, zA_h, nullptr, 64, 64, 192, 192, 1, 64, 1, 0, 3, p1t, 192, 192,
       1.f);
  stats_tiles(64, 36864, 576);                                    // zA stats -> meanb
  conv(zA_h, 11, r2b_b2, zB_h, nullptr, 64, 64, 192, 192, 1, 64, 1, 0, 1, nullptr, 192, 192,
       1.f);
  stats_tiles(64, 36864, 576);                                    // zB stats -> meanb

  // ---- pred head: norm(zB) -> 64 -> 1 + sigmoid -> d_out (NCHW [2,1,192,192]) ----
  pred_kernel<<<dim3(144, 2), TPB, 0, stream>>>(zB_h, pred_w, pred_b, meanb, invb, outp);
}